// Round 3
// baseline (2381.955 us; speedup 1.0000x reference)
//
#include <hip/hip_runtime.h>
#include <cstdint>
#include <cstddef>

#define KS 5
#define K3 125

__device__ __forceinline__ unsigned f2ord(float f){
    unsigned u = __float_as_uint(f);
    return (u & 0x80000000u) ? ~u : (u | 0x80000000u);
}
__device__ __forceinline__ float ord2f(unsigned u){
    unsigned b = (u & 0x80000000u) ? (u & 0x7FFFFFFFu) : ~u;
    return __uint_as_float(b);
}

// ---------------- degree histogram ----------------
__global__ void k_deg(const int* __restrict__ dst, int E, int* __restrict__ deg){
    int e = blockIdx.x*blockDim.x + threadIdx.x;
    if(e < E) atomicAdd(&deg[dst[e]], 1);
}

// ---------------- single-block exclusive scan -> rowptr + cursor ----------------
__global__ __launch_bounds__(1024) void k_scan(const int* __restrict__ deg, int N, int E,
        int* __restrict__ rowptr, int* __restrict__ cursor){
    __shared__ int part[1024];
    int tid = threadIdx.x;
    int C = (N + 1023) >> 10;
    int base = tid*C;
    int s = 0;
    for(int i=0;i<C;i++){ int idx=base+i; if(idx<N) s += deg[idx]; }
    part[tid] = s;
    __syncthreads();
    for(int off=1; off<1024; off<<=1){
        int v = (tid>=off) ? part[tid-off] : 0;
        __syncthreads();
        part[tid] += v;
        __syncthreads();
    }
    int run = (tid==0) ? 0 : part[tid-1];
    for(int i=0;i<C;i++){
        int idx=base+i;
        if(idx<N){ rowptr[idx]=run; cursor[idx]=run; run+=deg[idx]; }
    }
    if(tid==0) rowptr[N] = E;
}

// ---------------- CSR fill ----------------
__global__ void k_fill(const int* __restrict__ dst, int E,
                       int* __restrict__ cursor, int* __restrict__ elist){
    int e = blockIdx.x*blockDim.x + threadIdx.x;
    if(e < E){
        int p = atomicAdd(&cursor[dst[e]], 1);
        elist[p] = e;
    }
}

// ---------------- build A rows in LDS (no global atomics, no memset) ----------------
// block = 256 threads, NB nodes per block, row = K3*CIN floats in LDS.
// TPN = 256/NB threads per node, organized as GPN = TPN/CIN edge-groups x CIN ci-lanes.
template<int CIN, int NB>
__global__ __launch_bounds__(256) void k_build(const int* __restrict__ src,
        const float* __restrict__ pos, const float* __restrict__ x,
        const int* __restrict__ rowptr, const int* __restrict__ elist,
        float inv2r, int n0, int n1, float* __restrict__ A){
    const int KD  = K3*CIN;
    const int TPN = 256/NB;
    const int GPN = TPN/CIN;
    __shared__ float rows[NB*KD];
    int tid = threadIdx.x;
    for(int i=tid; i<NB*KD; i+=256) rows[i] = 0.f;
    __syncthreads();

    int nb  = tid / TPN;
    int lt  = tid - nb*TPN;
    int grp = lt / CIN;
    int ci  = lt - grp*CIN;
    int node = n0 + blockIdx.x*NB + nb;
    float* row = rows + nb*KD;

    if(node < n1 && grp < GPN){
        float pdx = pos[node*3+0], pdy = pos[node*3+1], pdz = pos[node*3+2];
        int e0 = rowptr[node], e1 = rowptr[node+1];
        for(int ii=e0+grp; ii<e1; ii+=GPN){
            int e = elist[ii];
            int s = src[e];
            float fr[3]; int k0[3];
            float ps0 = pos[s*3+0], ps1 = pos[s*3+1], ps2 = pos[s*3+2];
            float dd[3] = {pdx-ps0, pdy-ps1, pdz-ps2};
            #pragma unroll
            for(int dim=0; dim<3; dim++){
                float p = dd[dim]*inv2r + 0.5f;
                p = fminf(fmaxf(p, 0.f), 1.f);
                float u = p*4.0f;
                float kf = fminf(floorf(u), 3.f);
                fr[dim] = u - kf; k0[dim] = (int)kf;
            }
            float xs = x[(size_t)s*CIN + ci];
            #pragma unroll
            for(int bits=0; bits<8; bits++){
                float w = ((bits&1)? fr[0] : 1.f-fr[0])
                        * ((bits&2)? fr[1] : 1.f-fr[1])
                        * ((bits&4)? fr[2] : 1.f-fr[2]);
                int kidx = (k0[0]+(bits&1)) + KS*(k0[1]+((bits>>1)&1)) + KS*KS*(k0[2]+((bits>>2)&1));
                atomicAdd(&row[kidx*CIN + ci], w*xs);
            }
        }
    }
    __syncthreads();
    size_t gbase = (size_t)blockIdx.x*NB*KD;
    for(int i=tid; i<NB*KD; i+=256){
        int nbw = i / KD;
        if(n0 + blockIdx.x*NB + nbw < n1) A[gbase + i] = rows[i];
    }
}

// ---------------- einsum GEMM: acc[n0+m, co] += A[m, kk] * W[kk, co], split-K ----------------
#define TM 128
#define TN 32
#define KB 16
__global__ __launch_bounds__(256) void k_gemm(const float* __restrict__ A,
        const float* __restrict__ W, float* __restrict__ acc,
        int n0, int Co, int Kd, int Kper){
    __shared__ __align__(16) float As[KB][TM];
    __shared__ __align__(16) float Bs[KB][TN];
    int tid = threadIdx.x;
    int m0 = blockIdx.x*TM, n0b = blockIdx.y*TN;
    int kstart = blockIdx.z*Kper;
    int kend = min(Kd, kstart + Kper);
    int tm = tid & 31, tn = tid >> 5;
    float r[4][4];
    #pragma unroll
    for(int i=0;i<4;i++)
        #pragma unroll
        for(int j=0;j<4;j++) r[i][j]=0.f;

    for(int k0=kstart; k0<kend; k0+=KB){
        #pragma unroll
        for(int l=0;l<8;l++){
            int j = tid + 256*l;
            int m = j >> 4, kr = j & 15;
            int kk = k0 + kr;
            As[kr][m] = (kk < kend) ? A[(size_t)(m0+m)*Kd + kk] : 0.f;
        }
        #pragma unroll
        for(int l=0;l<2;l++){
            int j = tid + 256*l;
            int kr = j >> 5, n = j & 31;
            int kk = k0 + kr;
            Bs[kr][n] = (kk < kend) ? W[(size_t)kk*Co + n0b + n] : 0.f;
        }
        __syncthreads();
        #pragma unroll
        for(int kr=0; kr<KB; kr++){
            float4 a4 = *(const float4*)&As[kr][tm*4];
            float4 b4 = *(const float4*)&Bs[kr][tn*4];
            float av[4] = {a4.x, a4.y, a4.z, a4.w};
            float bv[4] = {b4.x, b4.y, b4.z, b4.w};
            #pragma unroll
            for(int i=0;i<4;i++)
                #pragma unroll
                for(int j=0;j<4;j++)
                    r[i][j] += av[i]*bv[j];
        }
        __syncthreads();
    }
    #pragma unroll
    for(int i=0;i<4;i++){
        int m = n0 + m0 + tm*4 + i;
        #pragma unroll
        for(int j=0;j<4;j++)
            atomicAdd(&acc[(size_t)m*Co + n0b + tn*4 + j], r[i][j]);
    }
}

// ---------------- conv epilogue: /deg + x@root + b, ELU, attention col0 ----------------
__global__ void k_finish(const float* __restrict__ acc, const int* __restrict__ deg,
        const float* __restrict__ xin, const float* __restrict__ root,
        const float* __restrict__ bias, const float* __restrict__ Wa,
        const float* __restrict__ ba, float* __restrict__ y,
        float* __restrict__ att, int N, int Cin, int Co){
    extern __shared__ float sm[];
    float* xs  = sm;        // Cin
    float* red = sm + Cin;  // Co
    int n = blockIdx.x, co = threadIdx.x;
    for(int c=co; c<Cin; c+=Co) xs[c] = xin[(size_t)n*Cin + c];
    __syncthreads();
    float v = acc[(size_t)n*Co + co] / (float)max(deg[n], 1);
    float rt = 0.f;
    for(int c=0; c<Cin; c++) rt += xs[c]*root[(size_t)c*Co + co];
    v += rt + bias[co];
    float yv = v > 0.f ? v : expm1f(v);
    y[(size_t)n*Co + co] = yv;
    if(att){
        red[co] = yv * Wa[co*2];
        __syncthreads();
        int cur = Co;
        while(cur > 1){
            int half = (cur+1) >> 1;
            if(co < cur-half) red[co] += red[co+half];
            __syncthreads();
            cur = half;
        }
        if(co==0) att[n] = red[0] + ba[0];
    }
}

// ---------------- pooling ----------------
__global__ void k_pool_init(unsigned* __restrict__ m_u, unsigned* __restrict__ sel,
        float* __restrict__ cntf, float* __restrict__ ppos, int nc){
    int i = blockIdx.x*blockDim.x + threadIdx.x;
    if(i<nc){
        m_u[i]=0u; sel[i]=0xFFFFFFFFu; cntf[i]=0.f;
        ppos[i*3]=0.f; ppos[i*3+1]=0.f; ppos[i*3+2]=0.f;
    }
}
__global__ void k_pool1(const float* __restrict__ att, const int* __restrict__ cl,
        unsigned* __restrict__ m_u, int n){
    int i = blockIdx.x*blockDim.x + threadIdx.x;
    if(i<n) atomicMax(&m_u[cl[i]], f2ord(att[i]));
}
__global__ void k_pool2(const float* __restrict__ att, const int* __restrict__ cl,
        const unsigned* __restrict__ m_u, unsigned* __restrict__ sel,
        float* __restrict__ cntf, float* __restrict__ ppos,
        const float* __restrict__ pos, int n){
    int i = blockIdx.x*blockDim.x + threadIdx.x;
    if(i>=n) return;
    int c = cl[i];
    if(f2ord(att[i]) >= m_u[c]) atomicMin(&sel[c], (unsigned)i);
    atomicAdd(&cntf[c], 1.f);
    atomicAdd(&ppos[c*3+0], pos[i*3+0]);
    atomicAdd(&ppos[c*3+1], pos[i*3+1]);
    atomicAdd(&ppos[c*3+2], pos[i*3+2]);
}
__global__ void k_pool3(const unsigned* __restrict__ sel, const float* __restrict__ cntf,
        const float* __restrict__ ppos, const float* __restrict__ x,
        float* __restrict__ xo, float* __restrict__ poso, int nc, int Co, int nmax){
    int t = blockIdx.x*blockDim.x + threadIdx.x;
    if(t >= nc*Co) return;
    int c = t / Co;
    int co = t - c*Co;
    unsigned s = min(sel[c], (unsigned)(nmax-1));
    xo[(size_t)c*Co + co] = x[(size_t)s*Co + co];
    if(co < 3) poso[c*3+co] = ppos[c*3+co] / fmaxf(cntf[c], 1.f);
}

// ---------------- final voxel max pool ----------------
__global__ void k_vox(const float* __restrict__ x, const float* __restrict__ pos,
        unsigned* __restrict__ mx_u, float* __restrict__ cnt8){
    int nidx = blockIdx.x, ch = threadIdx.x;  // 256 x 256
    int v0 = min(max((int)floorf(pos[nidx*3+0]+0.5f),0),1);
    int v1 = min(max((int)floorf(pos[nidx*3+1]+0.5f),0),1);
    int v2 = min(max((int)floorf(pos[nidx*3+2]+0.5f),0),1);
    int b = nidx >> 3;
    int cl = b*8 + v0*4 + v1*2 + v2;
    atomicMax(&mx_u[cl*256+ch], f2ord(x[nidx*256+ch]));
    if(ch==0) atomicAdd(&cnt8[cl], 1.f);
}

// ---------------- FC + log_softmax ----------------
__global__ __launch_bounds__(256) void k_fc(const unsigned* __restrict__ mx_u,
        const float* __restrict__ cnt8, const float* __restrict__ Wfc,
        const float* __restrict__ bfc, float* __restrict__ out){
    __shared__ float sred[10][256];
    int b = blockIdx.x, tid = threadIdx.x;
    float p[10];
    #pragma unroll
    for(int j=0;j<10;j++) p[j]=0.f;
    for(int idx=tid; idx<2048; idx+=256){
        int v = idx >> 8;
        float val = (cnt8[b*8+v] > 0.f) ? ord2f(mx_u[b*2048+idx]) : 0.f;
        const float* wr = &Wfc[idx*10];
        #pragma unroll
        for(int j=0;j<10;j++) p[j] += val*wr[j];
    }
    #pragma unroll
    for(int j=0;j<10;j++) sred[j][tid]=p[j];
    __syncthreads();
    for(int s=128;s>0;s>>=1){
        if(tid<s){
            #pragma unroll
            for(int j=0;j<10;j++) sred[j][tid]+=sred[j][tid+s];
        }
        __syncthreads();
    }
    if(tid==0){
        float lg[10], mx=-1e30f, se=0.f;
        for(int j=0;j<10;j++){ lg[j]=sred[j][0]+bfc[j]; mx=fmaxf(mx,lg[j]); }
        for(int j=0;j<10;j++) se += expf(lg[j]-mx);
        float lse = mx + logf(se);
        for(int j=0;j<10;j++) out[b*10+j] = lg[j]-lse;
    }
}

extern "C" void kernel_launch(void* const* d_in, const int* in_sizes, int n_in,
                              void* d_out, int out_size, void* d_ws, size_t ws_size,
                              hipStream_t stream){
    const float* x0   = (const float*)d_in[0];
    const float* pos0 = (const float*)d_in[1];
    const float *Wc[5], *rootc[5], *bc[5];
    for(int i=0;i<5;i++){
        Wc[i]    = (const float*)d_in[2+3*i];
        rootc[i] = (const float*)d_in[3+3*i];
        bc[i]    = (const float*)d_in[4+3*i];
    }
    const float *Wa[4], *ba[4];
    for(int i=0;i<4;i++){
        Wa[i] = (const float*)d_in[17+2*i];
        ba[i] = (const float*)d_in[18+2*i];
    }
    const float* Wfc = (const float*)d_in[25];
    const float* bfc = (const float*)d_in[26];
    const int* ei[5]; for(int i=0;i<5;i++) ei[i] = (const int*)d_in[27+i];
    const int* cl[4]; for(int i=0;i<4;i++) cl[i] = (const int*)d_in[32+i];

    const int NPG[5]   = {2048,512,128,32,8};
    const int chans[6] = {1,32,64,96,128,256};
    const float inv2r[5] = {5.f,5.f,4.f,2.f,1.f};
    const int B = 32;

    size_t off = 0;
    auto alloc = [&](size_t bytes)->void*{
        void* p = (char*)d_ws + off;
        off = (off + bytes + 255) & ~(size_t)255;
        return p;
    };
    float*    x_a    = (float*)   alloc((size_t)65536*32*4);
    float*    x_b    = (float*)   alloc((size_t)16384*32*4);
    float*    pos_a  = (float*)   alloc((size_t)16384*3*4);
    float*    pos_b  = (float*)   alloc((size_t)4096*3*4);
    float*    acc    = (float*)   alloc((size_t)65536*32*4);
    int*      deg    = (int*)     alloc((size_t)65536*4);
    float*    att    = (float*)   alloc((size_t)65536*4);
    unsigned* m_u    = (unsigned*)alloc((size_t)16384*4);
    unsigned* sel    = (unsigned*)alloc((size_t)16384*4);
    float*    cntf   = (float*)   alloc((size_t)16384*4);
    float*    ppos   = (float*)   alloc((size_t)16384*3*4);
    unsigned* mx_u   = (unsigned*)alloc((size_t)256*256*4);
    float*    cnt8   = (float*)   alloc((size_t)256*4);
    int*      rowptr = (int*)     alloc((size_t)(65536+1)*4);
    int*      cursor = (int*)     alloc((size_t)65536*4);
    int*      elist  = (int*)     alloc((size_t)1048576*4);
    float*    A      = (float*)((char*)d_ws + off);
    size_t Abudget   = (ws_size > off) ? (ws_size - off) : 0;

    const float* xin = x0;
    const float* pin = pos0;

    for(int L=0; L<5; L++){
        int N  = B*NPG[L];
        int E  = N*16;
        int Cin = chans[L], Co = chans[L+1];
        int Kd  = K3*Cin;
        const int* srcp = ei[L];
        const int* dstp = ei[L] + E;

        hipMemsetAsync(deg, 0, (size_t)N*4, stream);
        hipMemsetAsync(acc, 0, (size_t)N*Co*4, stream);
        k_deg<<<(E+255)/256, 256, 0, stream>>>(dstp, E, deg);
        k_scan<<<1, 1024, 0, stream>>>(deg, N, E, rowptr, cursor);
        k_fill<<<(E+255)/256, 256, 0, stream>>>(dstp, E, cursor, elist);

        // row-chunking: Mc nodes per chunk (multiple of TM), full Cin per chunk
        size_t nodeb = (size_t)Kd*4;
        int Mc = (int)(Abudget / nodeb);
        Mc = (Mc / TM) * TM;
        if(Mc < TM) Mc = TM;
        if(Mc > N) Mc = N;

        for(int rn0=0; rn0<N; rn0+=Mc){
            int rn1 = (rn0+Mc < N) ? rn0+Mc : N;
            int Mr  = rn1 - rn0;
            // build A rows in LDS, coalesced write-out
            if(Cin==1)        k_build<1,32> <<<(Mr+31)/32, 256, 0, stream>>>(srcp, pin, xin, rowptr, elist, inv2r[L], rn0, rn1, A);
            else if(Cin==32)  k_build<32,4> <<<(Mr+3)/4,   256, 0, stream>>>(srcp, pin, xin, rowptr, elist, inv2r[L], rn0, rn1, A);
            else if(Cin==64)  k_build<64,2> <<<(Mr+1)/2,   256, 0, stream>>>(srcp, pin, xin, rowptr, elist, inv2r[L], rn0, rn1, A);
            else if(Cin==96)  k_build<96,1> <<<Mr,         256, 0, stream>>>(srcp, pin, xin, rowptr, elist, inv2r[L], rn0, rn1, A);
            else              k_build<128,1><<<Mr,         256, 0, stream>>>(srcp, pin, xin, rowptr, elist, inv2r[L], rn0, rn1, A);

            int gx = Mr/TM, gy = Co/TN;
            int S = (768 + gx*gy - 1)/(gx*gy);
            int maxS = (Kd + 127)/128;
            if(S > maxS) S = maxS;
            if(S > 64) S = 64;
            if(S < 1) S = 1;
            int Kper = ((Kd + S - 1)/S + KB - 1)/KB*KB;
            dim3 g(gx, gy, S);
            k_gemm<<<g, 256, 0, stream>>>(A, Wc[L], acc, rn0, Co, Kd, Kper);
        }

        float* y = x_a;
        k_finish<<<N, Co, (size_t)(Cin+Co)*4, stream>>>(acc, deg, xin, rootc[L], bc[L],
            (L<4)?Wa[L]:nullptr, (L<4)?ba[L]:nullptr, y, (L<4)?att:nullptr, N, Cin, Co);

        if(L<4){
            int nc = B*NPG[L+1];
            float* pout = (L%2==0) ? pos_a : pos_b;
            k_pool_init<<<(nc+255)/256, 256, 0, stream>>>(m_u, sel, cntf, ppos, nc);
            k_pool1<<<(N+255)/256, 256, 0, stream>>>(att, cl[L], m_u, N);
            k_pool2<<<(N+255)/256, 256, 0, stream>>>(att, cl[L], m_u, sel, cntf, ppos, pin, N);
            k_pool3<<<(nc*Co+255)/256, 256, 0, stream>>>(sel, cntf, ppos, y, x_b, pout, nc, Co, N);
            xin = x_b; pin = pout;
        }
    }

    hipMemsetAsync(mx_u, 0, (size_t)256*256*4, stream);
    hipMemsetAsync(cnt8, 0, (size_t)256*4, stream);
    k_vox<<<256, 256, 0, stream>>>(x_a, pin, mx_u, cnt8);
    k_fc<<<32, 256, 0, stream>>>(mx_u, cnt8, Wfc, bfc, (float*)d_out);
}

// Round 4
// 1350.159 us; speedup vs baseline: 1.7642x; 1.7642x over previous
//
#include <hip/hip_runtime.h>
#include <cstdint>
#include <cstddef>

#define KS 5
#define K3 125

typedef __attribute__((ext_vector_type(8))) short bf16x8;
typedef __attribute__((ext_vector_type(4))) float f32x4;

__device__ __forceinline__ unsigned f2ord(float f){
    unsigned u = __float_as_uint(f);
    return (u & 0x80000000u) ? ~u : (u | 0x80000000u);
}
__device__ __forceinline__ float ord2f(unsigned u){
    unsigned b = (u & 0x80000000u) ? (u & 0x7FFFFFFFu) : ~u;
    return __uint_as_float(b);
}
__device__ __forceinline__ unsigned short f2bf(float f){
    unsigned u = __float_as_uint(f);
    u = (u + 0x7FFFu + ((u >> 16) & 1u)) >> 16;
    return (unsigned short)u;
}

// ---------------- degree histogram ----------------
__global__ void k_deg(const int* __restrict__ dst, int E, int* __restrict__ deg){
    int e = blockIdx.x*blockDim.x + threadIdx.x;
    if(e < E) atomicAdd(&deg[dst[e]], 1);
}

// ---------------- single-block exclusive scan -> rowptr + cursor ----------------
__global__ __launch_bounds__(1024) void k_scan(const int* __restrict__ deg, int N, int E,
        int* __restrict__ rowptr, int* __restrict__ cursor){
    __shared__ int part[1024];
    int tid = threadIdx.x;
    int C = (N + 1023) >> 10;
    int base = tid*C;
    int s = 0;
    for(int i=0;i<C;i++){ int idx=base+i; if(idx<N) s += deg[idx]; }
    part[tid] = s;
    __syncthreads();
    for(int off=1; off<1024; off<<=1){
        int v = (tid>=off) ? part[tid-off] : 0;
        __syncthreads();
        part[tid] += v;
        __syncthreads();
    }
    int run = (tid==0) ? 0 : part[tid-1];
    for(int i=0;i<C;i++){
        int idx=base+i;
        if(idx<N){ rowptr[idx]=run; cursor[idx]=run; run+=deg[idx]; }
    }
    if(tid==0) rowptr[N] = E;
}

// ---------------- CSR fill ----------------
__global__ void k_fill(const int* __restrict__ dst, int E,
                       int* __restrict__ cursor, int* __restrict__ elist){
    int e = blockIdx.x*blockDim.x + threadIdx.x;
    if(e < E){
        int p = atomicAdd(&cursor[dst[e]], 1);
        elist[p] = e;
    }
}

// ---------------- W transpose + bf16 convert: Wt[co][k] = bf16(W[k][co]) ----------------
__global__ __launch_bounds__(256) void k_wt(const float* __restrict__ W,
        unsigned short* __restrict__ Wt, int Kd, int KdP, int Co){
    __shared__ float t[64][65];
    int kb = blockIdx.x*64, cb = blockIdx.y*64;
    int tid = threadIdx.x;
    int cc = tid & 63, rg = tid >> 6;
    #pragma unroll
    for(int i=0;i<16;i++){
        int kl = rg + i*4;
        int kk = kb + kl, co = cb + cc;
        t[kl][cc] = (kk < Kd && co < Co) ? W[(size_t)kk*Co + co] : 0.f;
    }
    __syncthreads();
    int kl = tid & 63;
    #pragma unroll
    for(int i=0;i<16;i++){
        int col = rg + i*4;
        int co = cb + col;
        int kk = kb + kl;
        if(co < Co && kk < KdP) Wt[(size_t)co*KdP + kk] = f2bf(t[kl][col]);
    }
}

// ---------------- build A rows in LDS (fp32 accum), write bf16, stride KdP ----------------
template<int CIN, int NB>
__global__ __launch_bounds__(256) void k_build(const int* __restrict__ src,
        const float* __restrict__ pos, const float* __restrict__ x,
        const int* __restrict__ rowptr, const int* __restrict__ elist,
        float inv2r, int n0, int KdP, unsigned short* __restrict__ A){
    const int KD  = K3*CIN;
    const int TPN = 256/NB;
    const int CW  = (CIN < 32) ? CIN : 32;
    const int GPN = TPN/CW;
    __shared__ float rows[NB*KD];
    int tid = threadIdx.x;
    for(int i=tid; i<NB*KD; i+=256) rows[i] = 0.f;
    __syncthreads();

    int nb  = tid / TPN;
    int lt  = tid - nb*TPN;
    int grp = lt / CW;
    int cl  = lt - grp*CW;
    int node = n0 + blockIdx.x*NB + nb;
    float* row = rows + nb*KD;

    float pdx = pos[node*3+0], pdy = pos[node*3+1], pdz = pos[node*3+2];
    int e0 = rowptr[node], e1 = rowptr[node+1];
    for(int ii=e0+grp; ii<e1; ii+=GPN){
        int e = elist[ii];
        int s = src[e];
        float fr[3]; int k0[3];
        float dd[3] = {pdx - pos[s*3+0], pdy - pos[s*3+1], pdz - pos[s*3+2]};
        #pragma unroll
        for(int dim=0; dim<3; dim++){
            float p = dd[dim]*inv2r + 0.5f;
            p = fminf(fmaxf(p, 0.f), 1.f);
            float u = p*4.0f;
            float kf = fminf(floorf(u), 3.f);
            fr[dim] = u - kf; k0[dim] = (int)kf;
        }
        float wgt[8]; int ki[8];
        #pragma unroll
        for(int bits=0; bits<8; bits++){
            wgt[bits] = ((bits&1)? fr[0] : 1.f-fr[0])
                      * ((bits&2)? fr[1] : 1.f-fr[1])
                      * ((bits&4)? fr[2] : 1.f-fr[2]);
            ki[bits]  = (k0[0]+(bits&1)) + KS*(k0[1]+((bits>>1)&1)) + KS*KS*(k0[2]+((bits>>2)&1));
        }
        for(int ci=cl; ci<CIN; ci+=CW){
            float xs = x[(size_t)s*CIN + ci];
            #pragma unroll
            for(int b=0; b<8; b++)
                atomicAdd(&row[ki[b]*CIN + ci], wgt[b]*xs);
        }
    }
    __syncthreads();
    size_t gbase = (size_t)blockIdx.x*NB*KdP;
    if(KdP == KD){
        for(int i=tid*2; i<NB*KD; i+=512){
            unsigned pk = (unsigned)f2bf(rows[i]) | ((unsigned)f2bf(rows[i+1]) << 16);
            *(unsigned*)&A[gbase + i] = pk;
        }
    } else {
        int tot = NB*KdP;
        for(int i=tid*2; i<tot; i+=512){
            int nbw = i / KdP;
            int kk  = i - nbw*KdP;
            float v0 = (kk   < KD) ? rows[nbw*KD + kk]   : 0.f;
            float v1 = (kk+1 < KD) ? rows[nbw*KD + kk+1] : 0.f;
            unsigned pk = (unsigned)f2bf(v0) | ((unsigned)f2bf(v1) << 16);
            *(unsigned*)&A[gbase + i] = pk;
        }
    }
}

// ---------------- MFMA GEMM: acc[n0+m, co] (+)= A[m, k] * Wt[co, k], split-K ----------------
__global__ __launch_bounds__(256) void k_mfma(const unsigned short* __restrict__ A,
        const unsigned short* __restrict__ Wt, float* __restrict__ acc,
        int n0, int Co, int KdP, int Kper){
    __shared__ unsigned short Al[128*32];
    __shared__ unsigned short Bl[32*32];
    int tid = threadIdx.x;
    int m0 = blockIdx.x*128, nb0 = blockIdx.y*32;
    int kstart = blockIdx.z*Kper;
    int kend = min(KdP, kstart + Kper);
    if(kstart >= kend) return;
    int w = tid >> 6, l = tid & 63, lm = l & 15, lk = l >> 4;
    f32x4 c00 = {0,0,0,0}, c01 = {0,0,0,0}, c10 = {0,0,0,0}, c11 = {0,0,0,0};
    int ar = tid >> 1, ah = (tid & 1)*16;
    int bn = tid >> 3, bk = (tid & 7)*4;

    for(int k0=kstart; k0<kend; k0+=32){
        const unsigned short* ga = A + (size_t)(m0+ar)*KdP + k0 + ah;
        *(uint4*)&Al[ar*32 + ah]     = *(const uint4*)ga;
        *(uint4*)&Al[ar*32 + ah + 8] = *(const uint4*)(ga + 8);
        const unsigned short* gb = Wt + (size_t)(nb0+bn)*KdP + k0 + bk;
        *(uint2*)&Bl[bn*32 + bk] = *(const uint2*)gb;
        __syncthreads();
        bf16x8 a0 = *(bf16x8*)&Al[(w*32 + lm)*32 + lk*8];
        bf16x8 a1 = *(bf16x8*)&Al[(w*32 + 16 + lm)*32 + lk*8];
        bf16x8 b0 = *(bf16x8*)&Bl[lm*32 + lk*8];
        bf16x8 b1 = *(bf16x8*)&Bl[(16 + lm)*32 + lk*8];
        c00 = __builtin_amdgcn_mfma_f32_16x16x32_bf16(a0, b0, c00, 0,0,0);
        c01 = __builtin_amdgcn_mfma_f32_16x16x32_bf16(a0, b1, c01, 0,0,0);
        c10 = __builtin_amdgcn_mfma_f32_16x16x32_bf16(a1, b0, c10, 0,0,0);
        c11 = __builtin_amdgcn_mfma_f32_16x16x32_bf16(a1, b1, c11, 0,0,0);
        __syncthreads();
    }
    int mb = n0 + m0 + w*32 + lk*4;
    if(gridDim.z == 1){
        #pragma unroll
        for(int r=0;r<4;r++){
            acc[(size_t)(mb+r)*Co + nb0 + lm]      = c00[r];
            acc[(size_t)(mb+r)*Co + nb0 + 16 + lm] = c01[r];
            acc[(size_t)(mb+16+r)*Co + nb0 + lm]      = c10[r];
            acc[(size_t)(mb+16+r)*Co + nb0 + 16 + lm] = c11[r];
        }
    } else {
        #pragma unroll
        for(int r=0;r<4;r++){
            atomicAdd(&acc[(size_t)(mb+r)*Co + nb0 + lm],      c00[r]);
            atomicAdd(&acc[(size_t)(mb+r)*Co + nb0 + 16 + lm], c01[r]);
            atomicAdd(&acc[(size_t)(mb+16+r)*Co + nb0 + lm],      c10[r]);
            atomicAdd(&acc[(size_t)(mb+16+r)*Co + nb0 + 16 + lm], c11[r]);
        }
    }
}

// ---------------- conv epilogue: /deg + x@root + b, ELU, attention col0 ----------------
__global__ void k_finish(const float* __restrict__ acc, const int* __restrict__ deg,
        const float* __restrict__ xin, const float* __restrict__ root,
        const float* __restrict__ bias, const float* __restrict__ Wa,
        const float* __restrict__ ba, float* __restrict__ y,
        float* __restrict__ att, int N, int Cin, int Co){
    extern __shared__ float sm[];
    float* xs  = sm;        // Cin
    float* red = sm + Cin;  // Co
    int n = blockIdx.x, co = threadIdx.x;
    for(int c=co; c<Cin; c+=Co) xs[c] = xin[(size_t)n*Cin + c];
    __syncthreads();
    float v = acc[(size_t)n*Co + co] / (float)max(deg[n], 1);
    float rt = 0.f;
    for(int c=0; c<Cin; c++) rt += xs[c]*root[(size_t)c*Co + co];
    v += rt + bias[co];
    float yv = v > 0.f ? v : expm1f(v);
    y[(size_t)n*Co + co] = yv;
    if(att){
        red[co] = yv * Wa[co*2];
        __syncthreads();
        int cur = Co;
        while(cur > 1){
            int half = (cur+1) >> 1;
            if(co < cur-half) red[co] += red[co+half];
            __syncthreads();
            cur = half;
        }
        if(co==0) att[n] = red[0] + ba[0];
    }
}

// ---------------- pooling ----------------
__global__ void k_pool_init(unsigned* __restrict__ m_u, unsigned* __restrict__ sel,
        float* __restrict__ cntf, float* __restrict__ ppos, int nc){
    int i = blockIdx.x*blockDim.x + threadIdx.x;
    if(i<nc){
        m_u[i]=0u; sel[i]=0xFFFFFFFFu; cntf[i]=0.f;
        ppos[i*3]=0.f; ppos[i*3+1]=0.f; ppos[i*3+2]=0.f;
    }
}
__global__ void k_pool1(const float* __restrict__ att, const int* __restrict__ cl,
        unsigned* __restrict__ m_u, int n){
    int i = blockIdx.x*blockDim.x + threadIdx.x;
    if(i<n) atomicMax(&m_u[cl[i]], f2ord(att[i]));
}
__global__ void k_pool2(const float* __restrict__ att, const int* __restrict__ cl,
        const unsigned* __restrict__ m_u, unsigned* __restrict__ sel,
        float* __restrict__ cntf, float* __restrict__ ppos,
        const float* __restrict__ pos, int n){
    int i = blockIdx.x*blockDim.x + threadIdx.x;
    if(i>=n) return;
    int c = cl[i];
    if(f2ord(att[i]) >= m_u[c]) atomicMin(&sel[c], (unsigned)i);
    atomicAdd(&cntf[c], 1.f);
    atomicAdd(&ppos[c*3+0], pos[i*3+0]);
    atomicAdd(&ppos[c*3+1], pos[i*3+1]);
    atomicAdd(&ppos[c*3+2], pos[i*3+2]);
}
__global__ void k_pool3(const unsigned* __restrict__ sel, const float* __restrict__ cntf,
        const float* __restrict__ ppos, const float* __restrict__ x,
        float* __restrict__ xo, float* __restrict__ poso, int nc, int Co, int nmax){
    int t = blockIdx.x*blockDim.x + threadIdx.x;
    if(t >= nc*Co) return;
    int c = t / Co;
    int co = t - c*Co;
    unsigned s = min(sel[c], (unsigned)(nmax-1));
    xo[(size_t)c*Co + co] = x[(size_t)s*Co + co];
    if(co < 3) poso[c*3+co] = ppos[c*3+co] / fmaxf(cntf[c], 1.f);
}

// ---------------- final voxel max pool ----------------
__global__ void k_vox(const float* __restrict__ x, const float* __restrict__ pos,
        unsigned* __restrict__ mx_u, float* __restrict__ cnt8){
    int nidx = blockIdx.x, ch = threadIdx.x;  // 256 x 256
    int v0 = min(max((int)floorf(pos[nidx*3+0]+0.5f),0),1);
    int v1 = min(max((int)floorf(pos[nidx*3+1]+0.5f),0),1);
    int v2 = min(max((int)floorf(pos[nidx*3+2]+0.5f),0),1);
    int b = nidx >> 3;
    int cl = b*8 + v0*4 + v1*2 + v2;
    atomicMax(&mx_u[cl*256+ch], f2ord(x[nidx*256+ch]));
    if(ch==0) atomicAdd(&cnt8[cl], 1.f);
}

// ---------------- FC + log_softmax ----------------
__global__ __launch_bounds__(256) void k_fc(const unsigned* __restrict__ mx_u,
        const float* __restrict__ cnt8, const float* __restrict__ Wfc,
        const float* __restrict__ bfc, float* __restrict__ out){
    __shared__ float sred[10][256];
    int b = blockIdx.x, tid = threadIdx.x;
    float p[10];
    #pragma unroll
    for(int j=0;j<10;j++) p[j]=0.f;
    for(int idx=tid; idx<2048; idx+=256){
        int v = idx >> 8;
        float val = (cnt8[b*8+v] > 0.f) ? ord2f(mx_u[b*2048+idx]) : 0.f;
        const float* wr = &Wfc[idx*10];
        #pragma unroll
        for(int j=0;j<10;j++) p[j] += val*wr[j];
    }
    #pragma unroll
    for(int j=0;j<10;j++) sred[j][tid]=p[j];
    __syncthreads();
    for(int s=128;s>0;s>>=1){
        if(tid<s){
            #pragma unroll
            for(int j=0;j<10;j++) sred[j][tid]+=sred[j][tid+s];
        }
        __syncthreads();
    }
    if(tid==0){
        float lg[10], mx=-1e30f, se=0.f;
        for(int j=0;j<10;j++){ lg[j]=sred[j][0]+bfc[j]; mx=fmaxf(mx,lg[j]); }
        for(int j=0;j<10;j++) se += expf(lg[j]-mx);
        float lse = mx + logf(se);
        for(int j=0;j<10;j++) out[b*10+j] = lg[j]-lse;
    }
}

extern "C" void kernel_launch(void* const* d_in, const int* in_sizes, int n_in,
                              void* d_out, int out_size, void* d_ws, size_t ws_size,
                              hipStream_t stream){
    const float* x0   = (const float*)d_in[0];
    const float* pos0 = (const float*)d_in[1];
    const float *Wc[5], *rootc[5], *bc[5];
    for(int i=0;i<5;i++){
        Wc[i]    = (const float*)d_in[2+3*i];
        rootc[i] = (const float*)d_in[3+3*i];
        bc[i]    = (const float*)d_in[4+3*i];
    }
    const float *Wa[4], *ba[4];
    for(int i=0;i<4;i++){
        Wa[i] = (const float*)d_in[17+2*i];
        ba[i] = (const float*)d_in[18+2*i];
    }
    const float* Wfc = (const float*)d_in[25];
    const float* bfc = (const float*)d_in[26];
    const int* ei[5]; for(int i=0;i<5;i++) ei[i] = (const int*)d_in[27+i];
    const int* cl[4]; for(int i=0;i<4;i++) cl[i] = (const int*)d_in[32+i];

    const int NPG[5]   = {2048,512,128,32,8};
    const int chans[6] = {1,32,64,96,128,256};
    const float inv2r[5] = {5.f,5.f,4.f,2.f,1.f};
    const int B = 32;

    size_t off = 0;
    auto alloc = [&](size_t bytes)->void*{
        void* p = (char*)d_ws + off;
        off = (off + bytes + 255) & ~(size_t)255;
        return p;
    };
    float*    x_a    = (float*)   alloc((size_t)65536*32*4);
    float*    x_b    = (float*)   alloc((size_t)16384*32*4);
    float*    pos_a  = (float*)   alloc((size_t)16384*3*4);
    float*    pos_b  = (float*)   alloc((size_t)4096*3*4);
    float*    acc    = (float*)   alloc((size_t)65536*32*4);
    int*      deg    = (int*)     alloc((size_t)65536*4);
    float*    att    = (float*)   alloc((size_t)65536*4);
    unsigned* m_u    = (unsigned*)alloc((size_t)16384*4);
    unsigned* sel    = (unsigned*)alloc((size_t)16384*4);
    float*    cntf   = (float*)   alloc((size_t)16384*4);
    float*    ppos   = (float*)   alloc((size_t)16384*3*4);
    unsigned* mx_u   = (unsigned*)alloc((size_t)256*256*4);
    float*    cnt8   = (float*)   alloc((size_t)256*4);
    int*      rowptr = (int*)     alloc((size_t)(65536+1)*4);
    int*      cursor = (int*)     alloc((size_t)65536*4);
    int*      elist  = (int*)     alloc((size_t)1048576*4);
    unsigned short* Wt = (unsigned short*)alloc((size_t)256*16000*2);
    unsigned short* A  = (unsigned short*)((char*)d_ws + off);
    size_t Abudget   = (ws_size > off) ? (ws_size - off) : 0;

    const float* xin = x0;
    const float* pin = pos0;

    for(int L=0; L<5; L++){
        int N  = B*NPG[L];
        int E  = N*16;
        int Cin = chans[L], Co = chans[L+1];
        int Kd  = K3*Cin;
        int KdP = (Kd + 31) & ~31;
        const int* srcp = ei[L];
        const int* dstp = ei[L] + E;

        hipMemsetAsync(deg, 0, (size_t)N*4, stream);
        hipMemsetAsync(acc, 0, (size_t)N*Co*4, stream);
        k_deg<<<(E+255)/256, 256, 0, stream>>>(dstp, E, deg);
        k_scan<<<1, 1024, 0, stream>>>(deg, N, E, rowptr, cursor);
        k_fill<<<(E+255)/256, 256, 0, stream>>>(dstp, E, cursor, elist);

        dim3 gw((KdP+63)/64, (Co+63)/64);
        k_wt<<<gw, 256, 0, stream>>>(Wc[L], Wt, Kd, KdP, Co);

        // row chunking (full rows, bf16 A with stride KdP)
        size_t nodeb = (size_t)KdP*2;
        int Mc = (int)(Abudget / nodeb);
        Mc = (Mc / 128) * 128;
        if(Mc < 128) Mc = 128;
        if(Mc > N) Mc = N;

        for(int rn0=0; rn0<N; rn0+=Mc){
            int rn1 = (rn0+Mc < N) ? rn0+Mc : N;
            int Mr  = rn1 - rn0;
            if(Cin==1)        k_build<1,32> <<<Mr/32, 256, 0, stream>>>(srcp, pin, xin, rowptr, elist, inv2r[L], rn0, KdP, A);
            else if(Cin==32)  k_build<32,1> <<<Mr,    256, 0, stream>>>(srcp, pin, xin, rowptr, elist, inv2r[L], rn0, KdP, A);
            else if(Cin==64)  k_build<64,1> <<<Mr,    256, 0, stream>>>(srcp, pin, xin, rowptr, elist, inv2r[L], rn0, KdP, A);
            else if(Cin==96)  k_build<96,1> <<<Mr,    256, 0, stream>>>(srcp, pin, xin, rowptr, elist, inv2r[L], rn0, KdP, A);
            else              k_build<128,1><<<Mr,    256, 0, stream>>>(srcp, pin, xin, rowptr, elist, inv2r[L], rn0, KdP, A);

            int gx = Mr/128, gy = Co/32;
            int S = 768/(gx*gy);
            if(S < 1) S = 1;
            int maxS = KdP/32;
            if(S > maxS) S = maxS;
            int Kper = ((KdP + S - 1)/S + 31) & ~31;
            S = (KdP + Kper - 1)/Kper;
            dim3 g(gx, gy, S);
            k_mfma<<<g, 256, 0, stream>>>(A, Wt, acc, rn0, Co, KdP, Kper);
        }

        float* y = x_a;
        k_finish<<<N, Co, (size_t)(Cin+Co)*4, stream>>>(acc, deg, xin, rootc[L], bc[L],
            (L<4)?Wa[L]:nullptr, (L<4)?ba[L]:nullptr, y, (L<4)?att:nullptr, N, Cin, Co);

        if(L<4){
            int nc = B*NPG[L+1];
            float* pout = (L%2==0) ? pos_a : pos_b;
            k_pool_init<<<(nc+255)/256, 256, 0, stream>>>(m_u, sel, cntf, ppos, nc);
            k_pool1<<<(N+255)/256, 256, 0, stream>>>(att, cl[L], m_u, N);
            k_pool2<<<(N+255)/256, 256, 0, stream>>>(att, cl[L], m_u, sel, cntf, ppos, pin, N);
            k_pool3<<<(nc*Co+255)/256, 256, 0, stream>>>(sel, cntf, ppos, y, x_b, pout, nc, Co, N);
            xin = x_b; pin = pout;
        }
    }

    hipMemsetAsync(mx_u, 0, (size_t)256*256*4, stream);
    hipMemsetAsync(cnt8, 0, (size_t)256*4, stream);
    k_vox<<<256, 256, 0, stream>>>(x_a, pin, mx_u, cnt8);
    k_fc<<<32, 256, 0, stream>>>(mx_u, cnt8, Wfc, bfc, (float*)d_out);
}

// Round 5
// 1009.877 us; speedup vs baseline: 2.3587x; 1.3370x over previous
//
#include <hip/hip_runtime.h>
#include <cstdint>
#include <cstddef>

#define KS 5
#define K3 125

typedef __attribute__((ext_vector_type(8))) short bf16x8;
typedef __attribute__((ext_vector_type(4))) float f32x4;

__device__ __forceinline__ unsigned f2ord(float f){
    unsigned u = __float_as_uint(f);
    return (u & 0x80000000u) ? ~u : (u | 0x80000000u);
}
__device__ __forceinline__ float ord2f(unsigned u){
    unsigned b = (u & 0x80000000u) ? (u & 0x7FFFFFFFu) : ~u;
    return __uint_as_float(b);
}
__device__ __forceinline__ unsigned short f2bf(float f){
    unsigned u = __float_as_uint(f);
    u = (u + 0x7FFFu + ((u >> 16) & 1u)) >> 16;
    return (unsigned short)u;
}

// ---------------- degree histogram ----------------
__global__ void k_deg(const int* __restrict__ dst, int E, int* __restrict__ deg){
    int e = blockIdx.x*blockDim.x + threadIdx.x;
    if(e < E) atomicAdd(&deg[dst[e]], 1);
}

// ---------------- single-block exclusive scan -> rowptr + cursor ----------------
__global__ __launch_bounds__(1024) void k_scan(const int* __restrict__ deg, int N, int E,
        int* __restrict__ rowptr, int* __restrict__ cursor){
    __shared__ int part[1024];
    int tid = threadIdx.x;
    int C = (N + 1023) >> 10;
    int base = tid*C;
    int s = 0;
    for(int i=0;i<C;i++){ int idx=base+i; if(idx<N) s += deg[idx]; }
    part[tid] = s;
    __syncthreads();
    for(int off=1; off<1024; off<<=1){
        int v = (tid>=off) ? part[tid-off] : 0;
        __syncthreads();
        part[tid] += v;
        __syncthreads();
    }
    int run = (tid==0) ? 0 : part[tid-1];
    for(int i=0;i<C;i++){
        int idx=base+i;
        if(idx<N){ rowptr[idx]=run; cursor[idx]=run; run+=deg[idx]; }
    }
    if(tid==0) rowptr[N] = E;
}

// ---------------- CSR fill ----------------
__global__ void k_fill(const int* __restrict__ dst, int E,
                       int* __restrict__ cursor, int* __restrict__ elist){
    int e = blockIdx.x*blockDim.x + threadIdx.x;
    if(e < E){
        int p = atomicAdd(&cursor[dst[e]], 1);
        elist[p] = e;
    }
}

// ---------------- W transpose + bf16 convert: Wt[co][k] = bf16(W[k][co]) ----------------
__global__ __launch_bounds__(256) void k_wt(const float* __restrict__ W,
        unsigned short* __restrict__ Wt, int Kd, int KdP, int Co){
    __shared__ float t[64][65];
    int kb = blockIdx.x*64, cb = blockIdx.y*64;
    int tid = threadIdx.x;
    int cc = tid & 63, rg = tid >> 6;
    #pragma unroll
    for(int i=0;i<16;i++){
        int kl = rg + i*4;
        int kk = kb + kl, co = cb + cc;
        t[kl][cc] = (kk < Kd && co < Co) ? W[(size_t)kk*Co + co] : 0.f;
    }
    __syncthreads();
    int kl = tid & 63;
    #pragma unroll
    for(int i=0;i<16;i++){
        int col = rg + i*4;
        int co = cb + col;
        int kk = kb + kl;
        if(co < Co && kk < KdP) Wt[(size_t)co*KdP + kk] = f2bf(t[kl][col]);
    }
}

// ---------------- spline basis helper ----------------
__device__ __forceinline__ void spline_meta(float dx, float dy, float dz, float inv2r,
        float* wgt, short* ki){
    float fr[3]; int k0[3];
    float dd[3] = {dx, dy, dz};
    #pragma unroll
    for(int dim=0; dim<3; dim++){
        float p = dd[dim]*inv2r + 0.5f;
        p = fminf(fmaxf(p, 0.f), 1.f);
        float u = p*4.0f;
        float kf = fminf(floorf(u), 3.f);
        fr[dim] = u - kf; k0[dim] = (int)kf;
    }
    #pragma unroll
    for(int bits=0; bits<8; bits++){
        wgt[bits] = ((bits&1)? fr[0] : 1.f-fr[0])
                  * ((bits&2)? fr[1] : 1.f-fr[1])
                  * ((bits&4)? fr[2] : 1.f-fr[2]);
        ki[bits]  = (short)((k0[0]+(bits&1)) + KS*(k0[1]+((bits>>1)&1)) + KS*KS*(k0[2]+((bits>>2)&1)));
    }
}

// ---------------- build A row, atomic-free (Cin >= 32), one node per block ----------------
// Phase 1: one lane per edge computes weights/kidx -> LDS meta.
// Phase 2: all threads stage x[src] rows into LDS.
// Phase 3: slot-ownership accumulate: group g (of 8) owns ki%8==g; 32 ci lanes.
template<int CIN>
__global__ __launch_bounds__(256) void k_build2(const int* __restrict__ src,
        const float* __restrict__ pos, const float* __restrict__ x,
        const int* __restrict__ rowptr, const int* __restrict__ elist,
        float inv2r, int n0, int KdP, unsigned short* __restrict__ A){
    const int KD = K3*CIN;
    const int CH = 64;
    __shared__ float row[KD];
    __shared__ float xbuf[CH*CIN];
    __shared__ float ew[CH][8];
    __shared__ short ek[CH][8];
    __shared__ int esrc[CH];
    int tid = threadIdx.x;
    int node = n0 + blockIdx.x;
    for(int i=tid; i<KD; i+=256) row[i] = 0.f;
    int e0 = rowptr[node], e1 = rowptr[node+1];
    float pdx = pos[node*3+0], pdy = pos[node*3+1], pdz = pos[node*3+2];

    for(int c0=e0; c0<e1; c0+=CH){
        int cnt = min(CH, e1-c0);
        __syncthreads();   // previous phase-3 / row init complete before meta overwrite
        if(tid < cnt){
            int e = elist[c0+tid];
            int s = src[e];
            esrc[tid] = s;
            float w[8]; short ki[8];
            spline_meta(pdx-pos[s*3+0], pdy-pos[s*3+1], pdz-pos[s*3+2], inv2r, w, ki);
            #pragma unroll
            for(int b=0;b<8;b++){ ew[tid][b]=w[b]; ek[tid][b]=ki[b]; }
        }
        __syncthreads();
        for(int i=tid; i<cnt*CIN; i+=256){
            int e = i/CIN, ci = i - e*CIN;
            xbuf[i] = x[(size_t)esrc[e]*CIN + ci];
        }
        __syncthreads();
        int g  = (tid >> 5) & 7;
        int cl = tid & 31;
        int np = cnt*8;
        for(int p=0; p<np; p++){
            int e = p >> 3, b = p & 7;
            int ki = ek[e][b];
            if((ki & 7) != g) continue;
            float w = ew[e][b];
            #pragma unroll
            for(int j=0; j<CIN/32; j++){
                int ci = cl + j*32;
                row[ki*CIN + ci] += w * xbuf[e*CIN + ci];
            }
        }
    }
    __syncthreads();
    size_t gbase = (size_t)blockIdx.x*KdP;
    for(int i=tid*2; i<KdP; i+=512){
        float v0 = (i   < KD) ? row[i]   : 0.f;
        float v1 = (i+1 < KD) ? row[i+1] : 0.f;
        unsigned pk = (unsigned)f2bf(v0) | ((unsigned)f2bf(v1) << 16);
        *(unsigned*)&A[gbase + i] = pk;
    }
}

// ---------------- build for Cin==1 (layer 1): 32 nodes/block, LDS atomics via hip builtin ----
__global__ __launch_bounds__(256) void k_build1(const int* __restrict__ src,
        const float* __restrict__ pos, const float* __restrict__ x,
        const int* __restrict__ rowptr, const int* __restrict__ elist,
        float inv2r, int n0, int KdP, unsigned short* __restrict__ A){
    const int NB = 32, KD = K3;
    __shared__ float rows[NB*KD];
    int tid = threadIdx.x;
    for(int i=tid; i<NB*KD; i+=256) rows[i] = 0.f;
    __syncthreads();
    int nb = tid >> 3;          // 8 lanes per node
    int grp = tid & 7;
    int node = n0 + blockIdx.x*NB + nb;
    float* row = rows + nb*KD;
    float pdx = pos[node*3+0], pdy = pos[node*3+1], pdz = pos[node*3+2];
    int e0 = rowptr[node], e1 = rowptr[node+1];
    for(int ii=e0+grp; ii<e1; ii+=8){
        int e = elist[ii];
        int s = src[e];
        float w[8]; short ki[8];
        spline_meta(pdx-pos[s*3+0], pdy-pos[s*3+1], pdz-pos[s*3+2], inv2r, w, ki);
        float xs = x[s];
        #pragma unroll
        for(int b=0; b<8; b++)
            __hip_atomic_fetch_add(&row[ki[b]], w[b]*xs, __ATOMIC_RELAXED, __HIP_MEMORY_SCOPE_WORKGROUP);
    }
    __syncthreads();
    size_t gbase = (size_t)blockIdx.x*NB*KdP;
    int tot = NB*KdP;
    for(int i=tid*2; i<tot; i+=512){
        int nbw = i / KdP;
        int kk  = i - nbw*KdP;
        float v0 = (kk   < KD) ? rows[nbw*KD + kk]   : 0.f;
        float v1 = (kk+1 < KD) ? rows[nbw*KD + kk+1] : 0.f;
        unsigned pk = (unsigned)f2bf(v0) | ((unsigned)f2bf(v1) << 16);
        *(unsigned*)&A[gbase + i] = pk;
    }
}

// ---------------- MFMA GEMM: acc[n0+m, co] (+)= A[m, k] * Wt[co, k], split-K ----------------
__global__ __launch_bounds__(256) void k_mfma(const unsigned short* __restrict__ A,
        const unsigned short* __restrict__ Wt, float* __restrict__ acc,
        int n0, int Co, int KdP, int Kper){
    __shared__ unsigned short Al[128*32];
    __shared__ unsigned short Bl[32*32];
    int tid = threadIdx.x;
    int m0 = blockIdx.x*128, nb0 = blockIdx.y*32;
    int kstart = blockIdx.z*Kper;
    int kend = min(KdP, kstart + Kper);
    if(kstart >= kend) return;
    int w = tid >> 6, l = tid & 63, lm = l & 15, lk = l >> 4;
    f32x4 c00 = {0,0,0,0}, c01 = {0,0,0,0}, c10 = {0,0,0,0}, c11 = {0,0,0,0};
    int ar = tid >> 1, ah = (tid & 1)*16;
    int bn = tid >> 3, bk = (tid & 7)*4;

    for(int k0=kstart; k0<kend; k0+=32){
        const unsigned short* ga = A + (size_t)(m0+ar)*KdP + k0 + ah;
        *(uint4*)&Al[ar*32 + ah]     = *(const uint4*)ga;
        *(uint4*)&Al[ar*32 + ah + 8] = *(const uint4*)(ga + 8);
        const unsigned short* gb = Wt + (size_t)(nb0+bn)*KdP + k0 + bk;
        *(uint2*)&Bl[bn*32 + bk] = *(const uint2*)gb;
        __syncthreads();
        bf16x8 a0 = *(bf16x8*)&Al[(w*32 + lm)*32 + lk*8];
        bf16x8 a1 = *(bf16x8*)&Al[(w*32 + 16 + lm)*32 + lk*8];
        bf16x8 b0 = *(bf16x8*)&Bl[lm*32 + lk*8];
        bf16x8 b1 = *(bf16x8*)&Bl[(16 + lm)*32 + lk*8];
        c00 = __builtin_amdgcn_mfma_f32_16x16x32_bf16(a0, b0, c00, 0,0,0);
        c01 = __builtin_amdgcn_mfma_f32_16x16x32_bf16(a0, b1, c01, 0,0,0);
        c10 = __builtin_amdgcn_mfma_f32_16x16x32_bf16(a1, b0, c10, 0,0,0);
        c11 = __builtin_amdgcn_mfma_f32_16x16x32_bf16(a1, b1, c11, 0,0,0);
        __syncthreads();
    }
    int mb = n0 + m0 + w*32 + lk*4;
    if(gridDim.z == 1){
        #pragma unroll
        for(int r=0;r<4;r++){
            acc[(size_t)(mb+r)*Co + nb0 + lm]      = c00[r];
            acc[(size_t)(mb+r)*Co + nb0 + 16 + lm] = c01[r];
            acc[(size_t)(mb+16+r)*Co + nb0 + lm]      = c10[r];
            acc[(size_t)(mb+16+r)*Co + nb0 + 16 + lm] = c11[r];
        }
    } else {
        #pragma unroll
        for(int r=0;r<4;r++){
            atomicAdd(&acc[(size_t)(mb+r)*Co + nb0 + lm],      c00[r]);
            atomicAdd(&acc[(size_t)(mb+r)*Co + nb0 + 16 + lm], c01[r]);
            atomicAdd(&acc[(size_t)(mb+16+r)*Co + nb0 + lm],      c10[r]);
            atomicAdd(&acc[(size_t)(mb+16+r)*Co + nb0 + 16 + lm], c11[r]);
        }
    }
}

// ---------------- conv epilogue: /deg + x@root + b, ELU, attention col0 ----------------
__global__ void k_finish(const float* __restrict__ acc, const int* __restrict__ deg,
        const float* __restrict__ xin, const float* __restrict__ root,
        const float* __restrict__ bias, const float* __restrict__ Wa,
        const float* __restrict__ ba, float* __restrict__ y,
        float* __restrict__ att, int N, int Cin, int Co){
    extern __shared__ float sm[];
    float* xs  = sm;        // Cin
    float* red = sm + Cin;  // Co
    int n = blockIdx.x, co = threadIdx.x;
    for(int c=co; c<Cin; c+=Co) xs[c] = xin[(size_t)n*Cin + c];
    __syncthreads();
    float v = acc[(size_t)n*Co + co] / (float)max(deg[n], 1);
    float rt = 0.f;
    for(int c=0; c<Cin; c++) rt += xs[c]*root[(size_t)c*Co + co];
    v += rt + bias[co];
    float yv = v > 0.f ? v : expm1f(v);
    y[(size_t)n*Co + co] = yv;
    if(att){
        red[co] = yv * Wa[co*2];
        __syncthreads();
        int cur = Co;
        while(cur > 1){
            int half = (cur+1) >> 1;
            if(co < cur-half) red[co] += red[co+half];
            __syncthreads();
            cur = half;
        }
        if(co==0) att[n] = red[0] + ba[0];
    }
}

// ---------------- pooling ----------------
__global__ void k_pool_init(unsigned* __restrict__ m_u, unsigned* __restrict__ sel,
        float* __restrict__ cntf, float* __restrict__ ppos, int nc){
    int i = blockIdx.x*blockDim.x + threadIdx.x;
    if(i<nc){
        m_u[i]=0u; sel[i]=0xFFFFFFFFu; cntf[i]=0.f;
        ppos[i*3]=0.f; ppos[i*3+1]=0.f; ppos[i*3+2]=0.f;
    }
}
__global__ void k_pool1(const float* __restrict__ att, const int* __restrict__ cl,
        unsigned* __restrict__ m_u, int n){
    int i = blockIdx.x*blockDim.x + threadIdx.x;
    if(i<n) atomicMax(&m_u[cl[i]], f2ord(att[i]));
}
__global__ void k_pool2(const float* __restrict__ att, const int* __restrict__ cl,
        const unsigned* __restrict__ m_u, unsigned* __restrict__ sel,
        float* __restrict__ cntf, float* __restrict__ ppos,
        const float* __restrict__ pos, int n){
    int i = blockIdx.x*blockDim.x + threadIdx.x;
    if(i>=n) return;
    int c = cl[i];
    if(f2ord(att[i]) >= m_u[c]) atomicMin(&sel[c], (unsigned)i);
    atomicAdd(&cntf[c], 1.f);
    atomicAdd(&ppos[c*3+0], pos[i*3+0]);
    atomicAdd(&ppos[c*3+1], pos[i*3+1]);
    atomicAdd(&ppos[c*3+2], pos[i*3+2]);
}
__global__ void k_pool3(const unsigned* __restrict__ sel, const float* __restrict__ cntf,
        const float* __restrict__ ppos, const float* __restrict__ x,
        float* __restrict__ xo, float* __restrict__ poso, int nc, int Co, int nmax){
    int t = blockIdx.x*blockDim.x + threadIdx.x;
    if(t >= nc*Co) return;
    int c = t / Co;
    int co = t - c*Co;
    unsigned s = min(sel[c], (unsigned)(nmax-1));
    xo[(size_t)c*Co + co] = x[(size_t)s*Co + co];
    if(co < 3) poso[c*3+co] = ppos[c*3+co] / fmaxf(cntf[c], 1.f);
}

// ---------------- final voxel max pool ----------------
__global__ void k_vox(const float* __restrict__ x, const float* __restrict__ pos,
        unsigned* __restrict__ mx_u, float* __restrict__ cnt8){
    int nidx = blockIdx.x, ch = threadIdx.x;  // 256 x 256
    int v0 = min(max((int)floorf(pos[nidx*3+0]+0.5f),0),1);
    int v1 = min(max((int)floorf(pos[nidx*3+1]+0.5f),0),1);
    int v2 = min(max((int)floorf(pos[nidx*3+2]+0.5f),0),1);
    int b = nidx >> 3;
    int cl = b*8 + v0*4 + v1*2 + v2;
    atomicMax(&mx_u[cl*256+ch], f2ord(x[nidx*256+ch]));
    if(ch==0) atomicAdd(&cnt8[cl], 1.f);
}

// ---------------- FC + log_softmax ----------------
__global__ __launch_bounds__(256) void k_fc(const unsigned* __restrict__ mx_u,
        const float* __restrict__ cnt8, const float* __restrict__ Wfc,
        const float* __restrict__ bfc, float* __restrict__ out){
    __shared__ float sred[10][256];
    int b = blockIdx.x, tid = threadIdx.x;
    float p[10];
    #pragma unroll
    for(int j=0;j<10;j++) p[j]=0.f;
    for(int idx=tid; idx<2048; idx+=256){
        int v = idx >> 8;
        float val = (cnt8[b*8+v] > 0.f) ? ord2f(mx_u[b*2048+idx]) : 0.f;
        const float* wr = &Wfc[idx*10];
        #pragma unroll
        for(int j=0;j<10;j++) p[j] += val*wr[j];
    }
    #pragma unroll
    for(int j=0;j<10;j++) sred[j][tid]=p[j];
    __syncthreads();
    for(int s=128;s>0;s>>=1){
        if(tid<s){
            #pragma unroll
            for(int j=0;j<10;j++) sred[j][tid]+=sred[j][tid+s];
        }
        __syncthreads();
    }
    if(tid==0){
        float lg[10], mx=-1e30f, se=0.f;
        for(int j=0;j<10;j++){ lg[j]=sred[j][0]+bfc[j]; mx=fmaxf(mx,lg[j]); }
        for(int j=0;j<10;j++) se += expf(lg[j]-mx);
        float lse = mx + logf(se);
        for(int j=0;j<10;j++) out[b*10+j] = lg[j]-lse;
    }
}

extern "C" void kernel_launch(void* const* d_in, const int* in_sizes, int n_in,
                              void* d_out, int out_size, void* d_ws, size_t ws_size,
                              hipStream_t stream){
    const float* x0   = (const float*)d_in[0];
    const float* pos0 = (const float*)d_in[1];
    const float *Wc[5], *rootc[5], *bc[5];
    for(int i=0;i<5;i++){
        Wc[i]    = (const float*)d_in[2+3*i];
        rootc[i] = (const float*)d_in[3+3*i];
        bc[i]    = (const float*)d_in[4+3*i];
    }
    const float *Wa[4], *ba[4];
    for(int i=0;i<4;i++){
        Wa[i] = (const float*)d_in[17+2*i];
        ba[i] = (const float*)d_in[18+2*i];
    }
    const float* Wfc = (const float*)d_in[25];
    const float* bfc = (const float*)d_in[26];
    const int* ei[5]; for(int i=0;i<5;i++) ei[i] = (const int*)d_in[27+i];
    const int* cl[4]; for(int i=0;i<4;i++) cl[i] = (const int*)d_in[32+i];

    const int NPG[5]   = {2048,512,128,32,8};
    const int chans[6] = {1,32,64,96,128,256};
    const float inv2r[5] = {5.f,5.f,4.f,2.f,1.f};
    const int B = 32;

    size_t off = 0;
    auto alloc = [&](size_t bytes)->void*{
        void* p = (char*)d_ws + off;
        off = (off + bytes + 255) & ~(size_t)255;
        return p;
    };
    float*    x_a    = (float*)   alloc((size_t)65536*32*4);
    float*    x_b    = (float*)   alloc((size_t)16384*32*4);
    float*    pos_a  = (float*)   alloc((size_t)16384*3*4);
    float*    pos_b  = (float*)   alloc((size_t)4096*3*4);
    float*    acc    = (float*)   alloc((size_t)65536*32*4);
    int*      deg    = (int*)     alloc((size_t)65536*4);
    float*    att    = (float*)   alloc((size_t)65536*4);
    unsigned* m_u    = (unsigned*)alloc((size_t)16384*4);
    unsigned* sel    = (unsigned*)alloc((size_t)16384*4);
    float*    cntf   = (float*)   alloc((size_t)16384*4);
    float*    ppos   = (float*)   alloc((size_t)16384*3*4);
    unsigned* mx_u   = (unsigned*)alloc((size_t)256*256*4);
    float*    cnt8   = (float*)   alloc((size_t)256*4);
    int*      rowptr = (int*)     alloc((size_t)(65536+1)*4);
    int*      cursor = (int*)     alloc((size_t)65536*4);
    int*      elist  = (int*)     alloc((size_t)1048576*4);
    unsigned short* Wt = (unsigned short*)alloc((size_t)256*16000*2);
    unsigned short* A  = (unsigned short*)((char*)d_ws + off);
    size_t Abudget   = (ws_size > off) ? (ws_size - off) : 0;

    const float* xin = x0;
    const float* pin = pos0;

    for(int L=0; L<5; L++){
        int N  = B*NPG[L];
        int E  = N*16;
        int Cin = chans[L], Co = chans[L+1];
        int Kd  = K3*Cin;
        int KdP = (Kd + 31) & ~31;
        const int* srcp = ei[L];
        const int* dstp = ei[L] + E;

        hipMemsetAsync(deg, 0, (size_t)N*4, stream);
        hipMemsetAsync(acc, 0, (size_t)N*Co*4, stream);
        k_deg<<<(E+255)/256, 256, 0, stream>>>(dstp, E, deg);
        k_scan<<<1, 1024, 0, stream>>>(deg, N, E, rowptr, cursor);
        k_fill<<<(E+255)/256, 256, 0, stream>>>(dstp, E, cursor, elist);

        dim3 gw((KdP+63)/64, (Co+63)/64);
        k_wt<<<gw, 256, 0, stream>>>(Wc[L], Wt, Kd, KdP, Co);

        // row chunking (full rows, bf16 A with stride KdP)
        size_t nodeb = (size_t)KdP*2;
        int Mc = (int)(Abudget / nodeb);
        Mc = (Mc / 128) * 128;
        if(Mc < 128) Mc = 128;
        if(Mc > N) Mc = N;

        for(int rn0=0; rn0<N; rn0+=Mc){
            int rn1 = (rn0+Mc < N) ? rn0+Mc : N;
            int Mr  = rn1 - rn0;
            if(Cin==1)        k_build1      <<<Mr/32, 256, 0, stream>>>(srcp, pin, xin, rowptr, elist, inv2r[L], rn0, KdP, A);
            else if(Cin==32)  k_build2<32>  <<<Mr,    256, 0, stream>>>(srcp, pin, xin, rowptr, elist, inv2r[L], rn0, KdP, A);
            else if(Cin==64)  k_build2<64>  <<<Mr,    256, 0, stream>>>(srcp, pin, xin, rowptr, elist, inv2r[L], rn0, KdP, A);
            else if(Cin==96)  k_build2<96>  <<<Mr,    256, 0, stream>>>(srcp, pin, xin, rowptr, elist, inv2r[L], rn0, KdP, A);
            else              k_build2<128> <<<Mr,    256, 0, stream>>>(srcp, pin, xin, rowptr, elist, inv2r[L], rn0, KdP, A);

            int gx = Mr/128, gy = Co/32;
            int S = 768/(gx*gy);
            if(S < 1) S = 1;
            int maxS = KdP/32;
            if(S > maxS) S = maxS;
            int Kper = ((KdP + S - 1)/S + 31) & ~31;
            S = (KdP + Kper - 1)/Kper;
            dim3 g(gx, gy, S);
            k_mfma<<<g, 256, 0, stream>>>(A, Wt, acc, rn0, Co, KdP, Kper);
        }

        float* y = x_a;
        k_finish<<<N, Co, (size_t)(Cin+Co)*4, stream>>>(acc, deg, xin, rootc[L], bc[L],
            (L<4)?Wa[L]:nullptr, (L<4)?ba[L]:nullptr, y, (L<4)?att:nullptr, N, Cin, Co);

        if(L<4){
            int nc = B*NPG[L+1];
            float* pout = (L%2==0) ? pos_a : pos_b;
            k_pool_init<<<(nc+255)/256, 256, 0, stream>>>(m_u, sel, cntf, ppos, nc);
            k_pool1<<<(N+255)/256, 256, 0, stream>>>(att, cl[L], m_u, N);
            k_pool2<<<(N+255)/256, 256, 0, stream>>>(att, cl[L], m_u, sel, cntf, ppos, pin, N);
            k_pool3<<<(nc*Co+255)/256, 256, 0, stream>>>(sel, cntf, ppos, y, x_b, pout, nc, Co, N);
            xin = x_b; pin = pout;
        }
    }

    hipMemsetAsync(mx_u, 0, (size_t)256*256*4, stream);
    hipMemsetAsync(cnt8, 0, (size_t)256*4, stream);
    k_vox<<<256, 256, 0, stream>>>(x_a, pin, mx_u, cnt8);
    k_fc<<<32, 256, 0, stream>>>(mx_u, cnt8, Wfc, bfc, (float*)d_out);
}

// Round 6
// 753.594 us; speedup vs baseline: 3.1608x; 1.3401x over previous
//
#include <hip/hip_runtime.h>
#include <cstdint>
#include <cstddef>

#define KS 5
#define K3 125

typedef __attribute__((ext_vector_type(8))) short bf16x8;
typedef __attribute__((ext_vector_type(4))) float f32x4;

struct CsrArgs {
    const int* dst[5];
    int* deg[5];
    int* rowptr[5];
    int* cursor[5];
    int* elist[5];
    int E[5];
    int N[5];
};
struct WtArgs {
    const float* W[5];
    unsigned short* Wt[5];
    int Kd[5], KdP[5], Co[5];
};

__device__ __forceinline__ unsigned f2ord(float f){
    unsigned u = __float_as_uint(f);
    return (u & 0x80000000u) ? ~u : (u | 0x80000000u);
}
__device__ __forceinline__ float ord2f(unsigned u){
    unsigned b = (u & 0x80000000u) ? (u & 0x7FFFFFFFu) : ~u;
    return __uint_as_float(b);
}
__device__ __forceinline__ unsigned short f2bf(float f){
    unsigned u = __float_as_uint(f);
    u = (u + 0x7FFFu + ((u >> 16) & 1u)) >> 16;
    return (unsigned short)u;
}

// ---------------- fused CSR build over all 5 layers ----------------
__global__ void k_deg_all(CsrArgs a){
    int l = blockIdx.y;
    int e = blockIdx.x*blockDim.x + threadIdx.x;
    if(e < a.E[l]) atomicAdd(&a.deg[l][a.dst[l][e]], 1);
}
__global__ __launch_bounds__(1024) void k_scan_all(CsrArgs a){
    __shared__ int part[1024];
    int l = blockIdx.x;
    const int* deg = a.deg[l];
    int* rowptr = a.rowptr[l];
    int* cursor = a.cursor[l];
    int N = a.N[l], E = a.E[l];
    int tid = threadIdx.x;
    int C = (N + 1023) >> 10;
    int base = tid*C;
    int s = 0;
    for(int i=0;i<C;i++){ int idx=base+i; if(idx<N) s += deg[idx]; }
    part[tid] = s;
    __syncthreads();
    for(int off=1; off<1024; off<<=1){
        int v = (tid>=off) ? part[tid-off] : 0;
        __syncthreads();
        part[tid] += v;
        __syncthreads();
    }
    int run = (tid==0) ? 0 : part[tid-1];
    for(int i=0;i<C;i++){
        int idx=base+i;
        if(idx<N){ rowptr[idx]=run; cursor[idx]=run; run+=deg[idx]; }
    }
    if(tid==0) rowptr[N] = E;
}
__global__ void k_fill_all(CsrArgs a){
    int l = blockIdx.y;
    int e = blockIdx.x*blockDim.x + threadIdx.x;
    if(e < a.E[l]){
        int p = atomicAdd(&a.cursor[l][a.dst[l][e]], 1);
        a.elist[l][p] = e;
    }
}

// ---------------- fused W transpose+bf16: Wt[co][k] = bf16(W[k][co]) ----------------
__global__ __launch_bounds__(256) void k_wt_all(WtArgs a){
    int l = blockIdx.z;
    int Kd = a.Kd[l], KdP = a.KdP[l], Co = a.Co[l];
    int kb = blockIdx.x*64, cb = blockIdx.y*64;
    if(kb >= KdP || cb >= Co) return;
    const float* W = a.W[l];
    unsigned short* Wt = a.Wt[l];
    __shared__ float t[64][65];
    int tid = threadIdx.x;
    int cc = tid & 63, rg = tid >> 6;
    #pragma unroll
    for(int i=0;i<16;i++){
        int kl = rg + i*4;
        int kk = kb + kl, co = cb + cc;
        t[kl][cc] = (kk < Kd && co < Co) ? W[(size_t)kk*Co + co] : 0.f;
    }
    __syncthreads();
    int kl = tid & 63;
    #pragma unroll
    for(int i=0;i<16;i++){
        int col = rg + i*4;
        int co = cb + col;
        int kk = kb + kl;
        if(co < Co && kk < KdP) Wt[(size_t)co*KdP + kk] = f2bf(t[kl][col]);
    }
}

// ---------------- spline basis helper ----------------
__device__ __forceinline__ void spline_meta(float dx, float dy, float dz, float inv2r,
        float* wgt, int* ki){
    float fr[3]; int k0[3];
    float dd[3] = {dx, dy, dz};
    #pragma unroll
    for(int dim=0; dim<3; dim++){
        float p = dd[dim]*inv2r + 0.5f;
        p = fminf(fmaxf(p, 0.f), 1.f);
        float u = p*4.0f;
        float kf = fminf(floorf(u), 3.f);
        fr[dim] = u - kf; k0[dim] = (int)kf;
    }
    #pragma unroll
    for(int bits=0; bits<8; bits++){
        wgt[bits] = ((bits&1)? fr[0] : 1.f-fr[0])
                  * ((bits&2)? fr[1] : 1.f-fr[1])
                  * ((bits&4)? fr[2] : 1.f-fr[2]);
        ki[bits]  = (k0[0]+(bits&1)) + KS*(k0[1]+((bits>>1)&1)) + KS*KS*(k0[2]+((bits>>2)&1));
    }
}

// ---------------- build A row, atomic-free + bucket-compacted (Cin >= 32) ----------------
template<int CIN>
__global__ __launch_bounds__(256) void k_build2(const int* __restrict__ src,
        const float* __restrict__ pos, const float* __restrict__ x,
        const int* __restrict__ rowptr, const int* __restrict__ elist,
        float inv2r, int n0, int KdP, unsigned short* __restrict__ A){
    const int KD = K3*CIN;
    const int CH = 64;
    __shared__ float row[KD];
    __shared__ float xbuf[CH*CIN];
    __shared__ float ew[CH][8];
    __shared__ int esrc[CH];
    __shared__ unsigned short bkt[8][2*CH];
    __shared__ int bcnt[8];
    int tid = threadIdx.x;
    int node = n0 + blockIdx.x;
    for(int i=tid; i<KD; i+=256) row[i] = 0.f;
    int e0 = rowptr[node], e1 = rowptr[node+1];
    float pdx = pos[node*3+0], pdy = pos[node*3+1], pdz = pos[node*3+2];

    for(int c0=e0; c0<e1; c0+=CH){
        int cnt = min(CH, e1-c0);
        __syncthreads();            // prev phase-3 done; meta/bkt safe to overwrite
        if(tid < 8) bcnt[tid] = 0;
        float w[8]; int ki[8];
        if(tid < cnt){
            int e = elist[c0+tid];
            int s = src[e];
            esrc[tid] = s;
            spline_meta(pdx-pos[s*3+0], pdy-pos[s*3+1], pdz-pos[s*3+2], inv2r, w, ki);
            #pragma unroll
            for(int b=0;b<8;b++) ew[tid][b]=w[b];
        }
        __syncthreads();            // bcnt reset + esrc visible
        if(tid < cnt){
            #pragma unroll
            for(int b=0;b<8;b++){
                int g = ki[b] & 7;
                int p = atomicAdd(&bcnt[g], 1);
                bkt[g][p] = (unsigned short)((ki[b]<<9) | (tid<<3) | b);
            }
        }
        for(int i=tid; i<cnt*CIN; i+=256){
            int e = i/CIN, ci = i - e*CIN;
            xbuf[i] = x[(size_t)esrc[e]*CIN + ci];
        }
        __syncthreads();            // buckets + xbuf ready
        int g  = (tid >> 5) & 7;
        int cl = tid & 31;
        int ng = bcnt[g];
        for(int i=0; i<ng; i++){
            unsigned v = bkt[g][i];
            int kq = v >> 9;
            int e  = (v >> 3) & 63;
            float wv = ew[e][v & 7];
            #pragma unroll
            for(int j=0; j<CIN/32; j++){
                int ci = cl + j*32;
                row[kq*CIN + ci] += wv * xbuf[e*CIN + ci];
            }
        }
    }
    __syncthreads();
    size_t gbase = (size_t)blockIdx.x*KdP;
    for(int i=tid*2; i<KdP; i+=512){
        float v0 = (i   < KD) ? row[i]   : 0.f;
        float v1 = (i+1 < KD) ? row[i+1] : 0.f;
        unsigned pk = (unsigned)f2bf(v0) | ((unsigned)f2bf(v1) << 16);
        *(unsigned*)&A[gbase + i] = pk;
    }
}

// ---------------- build for Cin==1 (layer 1): 32 nodes/block, LDS atomics ----------------
__global__ __launch_bounds__(256) void k_build1(const int* __restrict__ src,
        const float* __restrict__ pos, const float* __restrict__ x,
        const int* __restrict__ rowptr, const int* __restrict__ elist,
        float inv2r, int n0, int KdP, unsigned short* __restrict__ A){
    const int NB = 32, KD = K3;
    __shared__ float rows[NB*KD];
    int tid = threadIdx.x;
    for(int i=tid; i<NB*KD; i+=256) rows[i] = 0.f;
    __syncthreads();
    int nb = tid >> 3;
    int grp = tid & 7;
    int node = n0 + blockIdx.x*NB + nb;
    float* row = rows + nb*KD;
    float pdx = pos[node*3+0], pdy = pos[node*3+1], pdz = pos[node*3+2];
    int e0 = rowptr[node], e1 = rowptr[node+1];
    for(int ii=e0+grp; ii<e1; ii+=8){
        int e = elist[ii];
        int s = src[e];
        float w[8]; int ki[8];
        spline_meta(pdx-pos[s*3+0], pdy-pos[s*3+1], pdz-pos[s*3+2], inv2r, w, ki);
        float xs = x[s];
        #pragma unroll
        for(int b=0; b<8; b++)
            __hip_atomic_fetch_add(&row[ki[b]], w[b]*xs, __ATOMIC_RELAXED, __HIP_MEMORY_SCOPE_WORKGROUP);
    }
    __syncthreads();
    size_t gbase = (size_t)blockIdx.x*NB*KdP;
    int tot = NB*KdP;
    for(int i=tid*2; i<tot; i+=512){
        int nbw = i / KdP;
        int kk  = i - nbw*KdP;
        float v0 = (kk   < KD) ? rows[nbw*KD + kk]   : 0.f;
        float v1 = (kk+1 < KD) ? rows[nbw*KD + kk+1] : 0.f;
        unsigned pk = (unsigned)f2bf(v0) | ((unsigned)f2bf(v1) << 16);
        *(unsigned*)&A[gbase + i] = pk;
    }
}

// ---------------- MFMA GEMM: acc[n0+m, co] (+)= A[m, k] * Wt[co, k], split-K ----------------
template<int BN>
__global__ __launch_bounds__(256) void k_mfma(const unsigned short* __restrict__ A,
        const unsigned short* __restrict__ Wt, float* __restrict__ acc,
        int n0, int Co, int KdP, int Kper){
    const int NBF = BN/16;
    __shared__ unsigned short Al[128*32];
    __shared__ unsigned short Bl[BN*32];
    int tid = threadIdx.x;
    int m0 = blockIdx.x*128, nb0 = blockIdx.y*BN;
    int kstart = blockIdx.z*Kper;
    int kend = min(KdP, kstart + Kper);
    if(kstart >= kend) return;
    int w = tid >> 6, l = tid & 63, lm = l & 15, lk = l >> 4;
    f32x4 c[2][NBF];
    #pragma unroll
    for(int i=0;i<2;i++)
        #pragma unroll
        for(int j=0;j<NBF;j++) c[i][j] = (f32x4){0,0,0,0};
    int ar = tid >> 1, ah = (tid & 1)*16;
    int bn = tid >> 2, bk = (tid & 3)*8;

    for(int k0=kstart; k0<kend; k0+=32){
        const unsigned short* ga = A + (size_t)(m0+ar)*KdP + k0 + ah;
        *(uint4*)&Al[ar*32 + ah]     = *(const uint4*)ga;
        *(uint4*)&Al[ar*32 + ah + 8] = *(const uint4*)(ga + 8);
        if(tid < BN*4){
            const unsigned short* gb = Wt + (size_t)(nb0+bn)*KdP + k0 + bk;
            *(uint4*)&Bl[bn*32 + bk] = *(const uint4*)gb;
        }
        __syncthreads();
        bf16x8 af[2], bfr[NBF];
        #pragma unroll
        for(int i=0;i<2;i++) af[i] = *(bf16x8*)&Al[(w*32 + i*16 + lm)*32 + lk*8];
        #pragma unroll
        for(int j=0;j<NBF;j++) bfr[j] = *(bf16x8*)&Bl[(j*16 + lm)*32 + lk*8];
        #pragma unroll
        for(int i=0;i<2;i++)
            #pragma unroll
            for(int j=0;j<NBF;j++)
                c[i][j] = __builtin_amdgcn_mfma_f32_16x16x32_bf16(af[i], bfr[j], c[i][j], 0,0,0);
        __syncthreads();
    }
    #pragma unroll
    for(int i=0;i<2;i++){
        int mb = n0 + m0 + w*32 + i*16 + lk*4;
        #pragma unroll
        for(int j=0;j<NBF;j++){
            int col = nb0 + j*16 + lm;
            if(gridDim.z == 1){
                #pragma unroll
                for(int r=0;r<4;r++) acc[(size_t)(mb+r)*Co + col] = c[i][j][r];
            } else {
                #pragma unroll
                for(int r=0;r<4;r++) atomicAdd(&acc[(size_t)(mb+r)*Co + col], c[i][j][r]);
            }
        }
    }
}

// ---------------- conv epilogue: /deg + x@root + b, ELU, attention col0 ----------------
__global__ void k_finish2(const float* __restrict__ acc, const int* __restrict__ deg,
        const float* __restrict__ xin, const float* __restrict__ root,
        const float* __restrict__ bias, const float* __restrict__ Wa,
        const float* __restrict__ ba, float* __restrict__ y,
        float* __restrict__ att, int N, int Cin, int Co, int NPB){
    extern __shared__ float sm[];
    float* xs  = sm;             // NPB*Cin
    float* red = sm + NPB*Cin;   // NPB*Co
    int tid = threadIdx.x;
    int nl = tid / Co, co = tid - nl*Co;
    int n = blockIdx.x*NPB + nl;
    bool act = (n < N);
    if(act) for(int c=co; c<Cin; c+=Co) xs[nl*Cin + c] = xin[(size_t)n*Cin + c];
    __syncthreads();
    float yv = 0.f;
    if(act){
        float v = acc[(size_t)n*Co + co] / (float)max(deg[n], 1);
        float rt = 0.f;
        for(int c=0; c<Cin; c++) rt += xs[nl*Cin + c]*root[(size_t)c*Co + co];
        v += rt + bias[co];
        yv = v > 0.f ? v : expm1f(v);
        y[(size_t)n*Co + co] = yv;
    }
    if(att){
        red[tid] = act ? yv * Wa[co*2] : 0.f;
        __syncthreads();
        int cur = Co;
        while(cur > 1){
            int half = (cur+1) >> 1;
            if(co < cur-half) red[nl*Co + co] += red[nl*Co + co + half];
            __syncthreads();
            cur = half;
        }
        if(act && co==0) att[n] = red[nl*Co] + ba[0];
    }
}

// ---------------- pooling ----------------
__global__ void k_pool_init(unsigned* __restrict__ m_u, unsigned* __restrict__ sel,
        float* __restrict__ cntf, float* __restrict__ ppos, int nc){
    int i = blockIdx.x*blockDim.x + threadIdx.x;
    if(i<nc){
        m_u[i]=0u; sel[i]=0xFFFFFFFFu; cntf[i]=0.f;
        ppos[i*3]=0.f; ppos[i*3+1]=0.f; ppos[i*3+2]=0.f;
    }
}
__global__ void k_pool1(const float* __restrict__ att, const int* __restrict__ cl,
        unsigned* __restrict__ m_u, int n){
    int i = blockIdx.x*blockDim.x + threadIdx.x;
    if(i<n) atomicMax(&m_u[cl[i]], f2ord(att[i]));
}
__global__ void k_pool2(const float* __restrict__ att, const int* __restrict__ cl,
        const unsigned* __restrict__ m_u, unsigned* __restrict__ sel,
        float* __restrict__ cntf, float* __restrict__ ppos,
        const float* __restrict__ pos, int n){
    int i = blockIdx.x*blockDim.x + threadIdx.x;
    if(i>=n) return;
    int c = cl[i];
    if(f2ord(att[i]) >= m_u[c]) atomicMin(&sel[c], (unsigned)i);
    atomicAdd(&cntf[c], 1.f);
    atomicAdd(&ppos[c*3+0], pos[i*3+0]);
    atomicAdd(&ppos[c*3+1], pos[i*3+1]);
    atomicAdd(&ppos[c*3+2], pos[i*3+2]);
}
__global__ void k_pool3(const unsigned* __restrict__ sel, const float* __restrict__ cntf,
        const float* __restrict__ ppos, const float* __restrict__ x,
        float* __restrict__ xo, float* __restrict__ poso, int nc, int Co, int nmax){
    int t = blockIdx.x*blockDim.x + threadIdx.x;
    if(t >= nc*Co) return;
    int c = t / Co;
    int co = t - c*Co;
    unsigned s = min(sel[c], (unsigned)(nmax-1));
    xo[(size_t)c*Co + co] = x[(size_t)s*Co + co];
    if(co < 3) poso[c*3+co] = ppos[c*3+co] / fmaxf(cntf[c], 1.f);
}

// ---------------- final voxel max pool ----------------
__global__ void k_vox(const float* __restrict__ x, const float* __restrict__ pos,
        unsigned* __restrict__ mx_u, float* __restrict__ cnt8){
    int nidx = blockIdx.x, ch = threadIdx.x;
    int v0 = min(max((int)floorf(pos[nidx*3+0]+0.5f),0),1);
    int v1 = min(max((int)floorf(pos[nidx*3+1]+0.5f),0),1);
    int v2 = min(max((int)floorf(pos[nidx*3+2]+0.5f),0),1);
    int b = nidx >> 3;
    int cl = b*8 + v0*4 + v1*2 + v2;
    atomicMax(&mx_u[cl*256+ch], f2ord(x[nidx*256+ch]));
    if(ch==0) atomicAdd(&cnt8[cl], 1.f);
}

// ---------------- FC + log_softmax ----------------
__global__ __launch_bounds__(256) void k_fc(const unsigned* __restrict__ mx_u,
        const float* __restrict__ cnt8, const float* __restrict__ Wfc,
        const float* __restrict__ bfc, float* __restrict__ out){
    __shared__ float sred[10][256];
    int b = blockIdx.x, tid = threadIdx.x;
    float p[10];
    #pragma unroll
    for(int j=0;j<10;j++) p[j]=0.f;
    for(int idx=tid; idx<2048; idx+=256){
        int v = idx >> 8;
        float val = (cnt8[b*8+v] > 0.f) ? ord2f(mx_u[b*2048+idx]) : 0.f;
        const float* wr = &Wfc[idx*10];
        #pragma unroll
        for(int j=0;j<10;j++) p[j] += val*wr[j];
    }
    #pragma unroll
    for(int j=0;j<10;j++) sred[j][tid]=p[j];
    __syncthreads();
    for(int s=128;s>0;s>>=1){
        if(tid<s){
            #pragma unroll
            for(int j=0;j<10;j++) sred[j][tid]+=sred[j][tid+s];
        }
        __syncthreads();
    }
    if(tid==0){
        float lg[10], mx=-1e30f, se=0.f;
        for(int j=0;j<10;j++){ lg[j]=sred[j][0]+bfc[j]; mx=fmaxf(mx,lg[j]); }
        for(int j=0;j<10;j++) se += expf(lg[j]-mx);
        float lse = mx + logf(se);
        for(int j=0;j<10;j++) out[b*10+j] = lg[j]-lse;
    }
}

extern "C" void kernel_launch(void* const* d_in, const int* in_sizes, int n_in,
                              void* d_out, int out_size, void* d_ws, size_t ws_size,
                              hipStream_t stream){
    const float* x0   = (const float*)d_in[0];
    const float* pos0 = (const float*)d_in[1];
    const float *Wc[5], *rootc[5], *bc[5];
    for(int i=0;i<5;i++){
        Wc[i]    = (const float*)d_in[2+3*i];
        rootc[i] = (const float*)d_in[3+3*i];
        bc[i]    = (const float*)d_in[4+3*i];
    }
    const float *Wa[4], *ba[4];
    for(int i=0;i<4;i++){
        Wa[i] = (const float*)d_in[17+2*i];
        ba[i] = (const float*)d_in[18+2*i];
    }
    const float* Wfc = (const float*)d_in[25];
    const float* bfc = (const float*)d_in[26];
    const int* ei[5]; for(int i=0;i<5;i++) ei[i] = (const int*)d_in[27+i];
    const int* cl[4]; for(int i=0;i<4;i++) cl[i] = (const int*)d_in[32+i];

    const int NPG[5]   = {2048,512,128,32,8};
    const int chans[6] = {1,32,64,96,128,256};
    const float inv2r[5] = {5.f,5.f,4.f,2.f,1.f};
    const int B = 32;
    int Ns[5], Es[5], KdPs[5];
    int totN=0, totE=0, totWt=0;
    int nodeBase[5], edgeBase[5], wtBase[5];
    for(int l=0;l<5;l++){
        Ns[l] = B*NPG[l]; Es[l] = Ns[l]*16;
        int Kd = K3*chans[l];
        KdPs[l] = (Kd + 31) & ~31;
        nodeBase[l] = totN; totN += Ns[l];
        edgeBase[l] = totE; totE += Es[l];
        wtBase[l] = totWt; totWt += chans[l+1]*KdPs[l];
    }

    size_t off = 0;
    auto alloc = [&](size_t bytes)->void*{
        void* p = (char*)d_ws + off;
        off = (off + bytes + 255) & ~(size_t)255;
        return p;
    };
    float*    x_a    = (float*)   alloc((size_t)65536*32*4);
    float*    x_b    = (float*)   alloc((size_t)16384*32*4);
    float*    pos_a  = (float*)   alloc((size_t)16384*3*4);
    float*    pos_b  = (float*)   alloc((size_t)4096*3*4);
    float*    acc    = (float*)   alloc((size_t)65536*32*4);
    float*    att    = (float*)   alloc((size_t)65536*4);
    unsigned* m_u    = (unsigned*)alloc((size_t)16384*4);
    unsigned* sel    = (unsigned*)alloc((size_t)16384*4);
    float*    cntf   = (float*)   alloc((size_t)16384*4);
    float*    ppos   = (float*)   alloc((size_t)16384*3*4);
    unsigned* mx_u   = (unsigned*)alloc((size_t)256*256*4);
    float*    cnt8   = (float*)   alloc((size_t)256*4);
    int*      deg_a  = (int*)     alloc((size_t)totN*4);
    int*      rowp_a = (int*)     alloc((size_t)(totN+5)*4);
    int*      curs_a = (int*)     alloc((size_t)totN*4);
    int*      elist_a= (int*)     alloc((size_t)totE*4);
    unsigned short* Wt_a = (unsigned short*)alloc((size_t)totWt*2);
    unsigned short* A  = (unsigned short*)((char*)d_ws + off);
    size_t Abudget   = (ws_size > off) ? (ws_size - off) : 0;

    CsrArgs ca; WtArgs wa;
    for(int l=0;l<5;l++){
        ca.dst[l] = ei[l] + Es[l];
        ca.deg[l] = deg_a + nodeBase[l];
        ca.rowptr[l] = rowp_a + nodeBase[l] + l;
        ca.cursor[l] = curs_a + nodeBase[l];
        ca.elist[l] = elist_a + edgeBase[l];
        ca.E[l] = Es[l]; ca.N[l] = Ns[l];
        wa.W[l] = Wc[l]; wa.Wt[l] = Wt_a + wtBase[l];
        wa.Kd[l] = K3*chans[l]; wa.KdP[l] = KdPs[l]; wa.Co[l] = chans[l+1];
    }

    hipMemsetAsync(deg_a, 0, (size_t)totN*4, stream);
    k_deg_all<<<dim3(4096,5), 256, 0, stream>>>(ca);
    k_scan_all<<<5, 1024, 0, stream>>>(ca);
    k_fill_all<<<dim3(4096,5), 256, 0, stream>>>(ca);
    k_wt_all<<<dim3(250,4,5), 256, 0, stream>>>(wa);

    const float* xin = x0;
    const float* pin = pos0;

    for(int L=0; L<5; L++){
        int N  = Ns[L];
        int Cin = chans[L], Co = chans[L+1];
        int KdP = KdPs[L];
        const int* srcp = ei[L];
        const int* rowptrL = ca.rowptr[L];
        const int* elistL  = ca.elist[L];
        const unsigned short* WtL = wa.Wt[L];
        const int* degL = ca.deg[L];

        hipMemsetAsync(acc, 0, (size_t)N*Co*4, stream);

        size_t nodeb = (size_t)KdP*2;
        int Mc = (int)(Abudget / nodeb);
        Mc = (Mc / 128) * 128;
        if(Mc < 128) Mc = 128;
        if(Mc > N) Mc = N;

        for(int rn0=0; rn0<N; rn0+=Mc){
            int rn1 = (rn0+Mc < N) ? rn0+Mc : N;
            int Mr  = rn1 - rn0;
            if(Cin==1)        k_build1      <<<Mr/32, 256, 0, stream>>>(srcp, pin, xin, rowptrL, elistL, inv2r[L], rn0, KdP, A);
            else if(Cin==32)  k_build2<32>  <<<Mr,    256, 0, stream>>>(srcp, pin, xin, rowptrL, elistL, inv2r[L], rn0, KdP, A);
            else if(Cin==64)  k_build2<64>  <<<Mr,    256, 0, stream>>>(srcp, pin, xin, rowptrL, elistL, inv2r[L], rn0, KdP, A);
            else if(Cin==96)  k_build2<96>  <<<Mr,    256, 0, stream>>>(srcp, pin, xin, rowptrL, elistL, inv2r[L], rn0, KdP, A);
            else              k_build2<128> <<<Mr,    256, 0, stream>>>(srcp, pin, xin, rowptrL, elistL, inv2r[L], rn0, KdP, A);

            int BN = (Co % 64 == 0) ? 64 : 32;
            int gx = Mr/128, gy = Co/BN;
            int S = 768/(gx*gy);
            if(S < 1) S = 1;
            int maxS = KdP/32;
            if(S > maxS) S = maxS;
            int Kper = ((KdP + S - 1)/S + 31) & ~31;
            S = (KdP + Kper - 1)/Kper;
            dim3 g(gx, gy, S);
            if(BN == 64) k_mfma<64><<<g, 256, 0, stream>>>(A, WtL, acc, rn0, Co, KdP, Kper);
            else         k_mfma<32><<<g, 256, 0, stream>>>(A, WtL, acc, rn0, Co, KdP, Kper);
        }

        float* y = x_a;
        int NPB = 256/Co; if(NPB < 1) NPB = 1;
        int thr = NPB*Co;
        size_t smb = (size_t)(NPB*Cin + NPB*Co)*4;
        k_finish2<<<(N+NPB-1)/NPB, thr, smb, stream>>>(acc, degL, xin, rootc[L], bc[L],
            (L<4)?Wa[L]:nullptr, (L<4)?ba[L]:nullptr, y, (L<4)?att:nullptr, N, Cin, Co, NPB);

        if(L<4){
            int nc = Ns[L+1];
            float* pout = (L%2==0) ? pos_a : pos_b;
            k_pool_init<<<(nc+255)/256, 256, 0, stream>>>(m_u, sel, cntf, ppos, nc);
            k_pool1<<<(N+255)/256, 256, 0, stream>>>(att, cl[L], m_u, N);
            k_pool2<<<(N+255)/256, 256, 0, stream>>>(att, cl[L], m_u, sel, cntf, ppos, pin, N);
            k_pool3<<<(nc*Co+255)/256, 256, 0, stream>>>(sel, cntf, ppos, y, x_b, pout, nc, Co, N);
            xin = x_b; pin = pout;
        }
    }

    hipMemsetAsync(mx_u, 0, (size_t)256*256*4, stream);
    hipMemsetAsync(cnt8, 0, (size_t)256*4, stream);
    k_vox<<<256, 256, 0, stream>>>(x_a, pin, mx_u, cnt8);
    k_fc<<<32, 256, 0, stream>>>(mx_u, cnt8, Wfc, bfc, (float*)d_out);
}

// Round 7
// 603.770 us; speedup vs baseline: 3.9451x; 1.2481x over previous
//
#include <hip/hip_runtime.h>
#include <cstdint>
#include <cstddef>

#define KS 5
#define K3 125

typedef __attribute__((ext_vector_type(8))) short bf16x8;
typedef __attribute__((ext_vector_type(4))) float f32x4;

struct CsrArgs {
    const int* dst[5];
    int* deg[5];
    int* elist[5];
    int E[5];
    int N[5];
};
struct WtArgs {
    const float* W[5];
    unsigned short* Wt[5];
    int Kd[5], KdP[5], Co[5];
};
struct ScanTbl {
    int degOff[24]; int rpOff[24]; int curOff[24]; int cnt[24];
    int lfirst[6];
    int rpNOff[5]; int Eval[5];
};

__device__ __forceinline__ unsigned f2ord(float f){
    unsigned u = __float_as_uint(f);
    return (u & 0x80000000u) ? ~u : (u | 0x80000000u);
}
__device__ __forceinline__ float ord2f(unsigned u){
    unsigned b = (u & 0x80000000u) ? (u & 0x7FFFFFFFu) : ~u;
    return __uint_as_float(b);
}
__device__ __forceinline__ unsigned short f2bf(float f){
    unsigned u = __float_as_uint(f);
    u = (u + 0x7FFFu + ((u >> 16) & 1u)) >> 16;
    return (unsigned short)u;
}

// ---------------- degree histogram (all layers) ----------------
__global__ void k_deg_all(CsrArgs a){
    int l = blockIdx.y;
    int e = blockIdx.x*blockDim.x + threadIdx.x;
    if(e < a.E[l]) atomicAdd(&a.deg[l][a.dst[l][e]], 1);
}

// ---------------- hierarchical scan ----------------
__global__ __launch_bounds__(256) void k_scanA(ScanTbl t, const int* __restrict__ deg_a,
        int* __restrict__ rowp_a, int* __restrict__ bsum){
    __shared__ int part[256];
    int b = blockIdx.x;
    int n = t.cnt[b];
    const int* d = deg_a + t.degOff[b];
    int* rp = rowp_a + t.rpOff[b];
    int tid = threadIdx.x;
    int v[16]; int s = 0;
    #pragma unroll
    for(int j=0;j<16;j++){
        int idx = tid*16 + j;
        v[j] = (idx < n) ? d[idx] : 0;
        s += v[j];
    }
    part[tid] = s;
    __syncthreads();
    #pragma unroll
    for(int off=1; off<256; off<<=1){
        int val = (tid >= off) ? part[tid-off] : 0;
        __syncthreads();
        part[tid] += val;
        __syncthreads();
    }
    int run = tid ? part[tid-1] : 0;
    #pragma unroll
    for(int j=0;j<16;j++){
        int idx = tid*16 + j;
        if(idx < n){ rp[idx] = run; run += v[j]; }
    }
    if(tid == 255) bsum[b] = part[255];
}
__global__ void k_scanB(ScanTbl t, int* __restrict__ bsum, int* __restrict__ rowp_a){
    int l = threadIdx.x;
    if(l < 5){
        int run = 0;
        for(int b=t.lfirst[l]; b<t.lfirst[l+1]; b++){
            int tmp = bsum[b]; bsum[b] = run; run += tmp;
        }
        rowp_a[t.rpNOff[l]] = t.Eval[l];
    }
}
__global__ __launch_bounds__(256) void k_scanC(ScanTbl t, int* __restrict__ rowp_a,
        const int* __restrict__ bsum, int* __restrict__ curs_a){
    int b = blockIdx.x;
    int n = t.cnt[b];
    int off = bsum[b];
    int* rp = rowp_a + t.rpOff[b];
    int* cu = curs_a + t.curOff[b];
    for(int idx=threadIdx.x; idx<n; idx+=256){
        int val = rp[idx] + off;
        rp[idx] = val;
        cu[idx] = val;
    }
}

// ---------------- CSR fill (all layers) ----------------
__global__ void k_fill_all(CsrArgs a, int* __restrict__ curs_a, const int* nb0, const int* nb1,
        const int* nb2, const int* nb3, const int* nb4){
    // curs per layer passed via CsrArgs-like offsets: use deg slot trick instead
}
__global__ void k_fill_all2(CsrArgs a, int* curs0, int* curs1, int* curs2, int* curs3, int* curs4){
    int l = blockIdx.y;
    int* curs = (l==0)?curs0:(l==1)?curs1:(l==2)?curs2:(l==3)?curs3:curs4;
    int e = blockIdx.x*blockDim.x + threadIdx.x;
    if(e < a.E[l]){
        int p = atomicAdd(&curs[a.dst[l][e]], 1);
        a.elist[l][p] = e;
    }
}

// ---------------- fused W transpose+bf16 ----------------
__global__ __launch_bounds__(256) void k_wt_all(WtArgs a){
    int l = blockIdx.z;
    int Kd = a.Kd[l], KdP = a.KdP[l], Co = a.Co[l];
    int kb = blockIdx.x*64, cb = blockIdx.y*64;
    if(kb >= KdP || cb >= Co) return;
    const float* W = a.W[l];
    unsigned short* Wt = a.Wt[l];
    __shared__ float t[64][65];
    int tid = threadIdx.x;
    int cc = tid & 63, rg = tid >> 6;
    #pragma unroll
    for(int i=0;i<16;i++){
        int kl = rg + i*4;
        int kk = kb + kl, co = cb + cc;
        t[kl][cc] = (kk < Kd && co < Co) ? W[(size_t)kk*Co + co] : 0.f;
    }
    __syncthreads();
    int kl = tid & 63;
    #pragma unroll
    for(int i=0;i<16;i++){
        int col = rg + i*4;
        int co = cb + col;
        int kk = kb + kl;
        if(co < Co && kk < KdP) Wt[(size_t)co*KdP + kk] = f2bf(t[kl][col]);
    }
}

// ---------------- spline basis helper ----------------
__device__ __forceinline__ void spline_meta(float dx, float dy, float dz, float inv2r,
        float* wgt, int* ki){
    float fr[3]; int k0[3];
    float dd[3] = {dx, dy, dz};
    #pragma unroll
    for(int dim=0; dim<3; dim++){
        float p = dd[dim]*inv2r + 0.5f;
        p = fminf(fmaxf(p, 0.f), 1.f);
        float u = p*4.0f;
        float kf = fminf(floorf(u), 3.f);
        fr[dim] = u - kf; k0[dim] = (int)kf;
    }
    #pragma unroll
    for(int bits=0; bits<8; bits++){
        wgt[bits] = ((bits&1)? fr[0] : 1.f-fr[0])
                  * ((bits&2)? fr[1] : 1.f-fr[1])
                  * ((bits&4)? fr[2] : 1.f-fr[2]);
        ki[bits]  = (k0[0]+(bits&1)) + KS*(k0[1]+((bits>>1)&1)) + KS*KS*(k0[2]+((bits>>2)&1));
    }
}

// ---------------- build A row, atomic-free + bucket-compacted (Cin >= 32) ----------------
template<int CIN>
__global__ __launch_bounds__(256) void k_build2(const int* __restrict__ src,
        const float* __restrict__ pos, const float* __restrict__ x,
        const int* __restrict__ rowptr, const int* __restrict__ elist,
        float inv2r, int n0, int KdP, unsigned short* __restrict__ A){
    const int KD = K3*CIN;
    const int CH = 64;
    __shared__ float row[KD];
    __shared__ float xbuf[CH*CIN];
    __shared__ float ew[CH][8];
    __shared__ int esrc[CH];
    __shared__ unsigned short bkt[8][2*CH];
    __shared__ int bcnt[8];
    int tid = threadIdx.x;
    int node = n0 + blockIdx.x;
    for(int i=tid; i<KD; i+=256) row[i] = 0.f;
    int e0 = rowptr[node], e1 = rowptr[node+1];
    float pdx = pos[node*3+0], pdy = pos[node*3+1], pdz = pos[node*3+2];

    for(int c0=e0; c0<e1; c0+=CH){
        int cnt = min(CH, e1-c0);
        __syncthreads();
        if(tid < 8) bcnt[tid] = 0;
        float w[8]; int ki[8];
        if(tid < cnt){
            int e = elist[c0+tid];
            int s = src[e];
            esrc[tid] = s;
            spline_meta(pdx-pos[s*3+0], pdy-pos[s*3+1], pdz-pos[s*3+2], inv2r, w, ki);
            #pragma unroll
            for(int b=0;b<8;b++) ew[tid][b]=w[b];
        }
        __syncthreads();
        if(tid < cnt){
            #pragma unroll
            for(int b=0;b<8;b++){
                int g = ki[b] & 7;
                int p = atomicAdd(&bcnt[g], 1);
                bkt[g][p] = (unsigned short)((ki[b]<<9) | (tid<<3) | b);
            }
        }
        for(int i=tid; i<cnt*CIN; i+=256){
            int e = i/CIN, ci = i - e*CIN;
            xbuf[i] = x[(size_t)esrc[e]*CIN + ci];
        }
        __syncthreads();
        int g  = (tid >> 5) & 7;
        int cl = tid & 31;
        int ng = bcnt[g];
        for(int i=0; i<ng; i++){
            unsigned v = bkt[g][i];
            int kq = v >> 9;
            int e  = (v >> 3) & 63;
            float wv = ew[e][v & 7];
            #pragma unroll
            for(int j=0; j<CIN/32; j++){
                int ci = cl + j*32;
                row[kq*CIN + ci] += wv * xbuf[e*CIN + ci];
            }
        }
    }
    __syncthreads();
    size_t gbase = (size_t)blockIdx.x*KdP;
    for(int i=tid*2; i<KdP; i+=512){
        float v0 = (i   < KD) ? row[i]   : 0.f;
        float v1 = (i+1 < KD) ? row[i+1] : 0.f;
        unsigned pk = (unsigned)f2bf(v0) | ((unsigned)f2bf(v1) << 16);
        *(unsigned*)&A[gbase + i] = pk;
    }
}

// ---------------- build for Cin==1 (layer 1) ----------------
__global__ __launch_bounds__(256) void k_build1(const int* __restrict__ src,
        const float* __restrict__ pos, const float* __restrict__ x,
        const int* __restrict__ rowptr, const int* __restrict__ elist,
        float inv2r, int n0, int KdP, unsigned short* __restrict__ A){
    const int NB = 32, KD = K3;
    __shared__ float rows[NB*KD];
    int tid = threadIdx.x;
    for(int i=tid; i<NB*KD; i+=256) rows[i] = 0.f;
    __syncthreads();
    int nb = tid >> 3;
    int grp = tid & 7;
    int node = n0 + blockIdx.x*NB + nb;
    float* row = rows + nb*KD;
    float pdx = pos[node*3+0], pdy = pos[node*3+1], pdz = pos[node*3+2];
    int e0 = rowptr[node], e1 = rowptr[node+1];
    for(int ii=e0+grp; ii<e1; ii+=8){
        int e = elist[ii];
        int s = src[e];
        float w[8]; int ki[8];
        spline_meta(pdx-pos[s*3+0], pdy-pos[s*3+1], pdz-pos[s*3+2], inv2r, w, ki);
        float xs = x[s];
        #pragma unroll
        for(int b=0; b<8; b++)
            __hip_atomic_fetch_add(&row[ki[b]], w[b]*xs, __ATOMIC_RELAXED, __HIP_MEMORY_SCOPE_WORKGROUP);
    }
    __syncthreads();
    size_t gbase = (size_t)blockIdx.x*NB*KdP;
    int tot = NB*KdP;
    for(int i=tid*2; i<tot; i+=512){
        int nbw = i / KdP;
        int kk  = i - nbw*KdP;
        float v0 = (kk   < KD) ? rows[nbw*KD + kk]   : 0.f;
        float v1 = (kk+1 < KD) ? rows[nbw*KD + kk+1] : 0.f;
        unsigned pk = (unsigned)f2bf(v0) | ((unsigned)f2bf(v1) << 16);
        *(unsigned*)&A[gbase + i] = pk;
    }
}

// ---------------- MFMA GEMM ----------------
template<int BN>
__global__ __launch_bounds__(256) void k_mfma(const unsigned short* __restrict__ A,
        const unsigned short* __restrict__ Wt, float* __restrict__ acc,
        int n0, int Co, int KdP, int Kper){
    const int NBF = BN/16;
    __shared__ unsigned short Al[128*32];
    __shared__ unsigned short Bl[BN*32];
    int tid = threadIdx.x;
    int m0 = blockIdx.x*128, nb0 = blockIdx.y*BN;
    int kstart = blockIdx.z*Kper;
    int kend = min(KdP, kstart + Kper);
    if(kstart >= kend) return;
    int w = tid >> 6, l = tid & 63, lm = l & 15, lk = l >> 4;
    f32x4 c[2][NBF];
    #pragma unroll
    for(int i=0;i<2;i++)
        #pragma unroll
        for(int j=0;j<NBF;j++) c[i][j] = (f32x4){0,0,0,0};
    int ar = tid >> 1, ah = (tid & 1)*16;
    int bn = tid >> 2, bk = (tid & 3)*8;

    for(int k0=kstart; k0<kend; k0+=32){
        const unsigned short* ga = A + (size_t)(m0+ar)*KdP + k0 + ah;
        *(uint4*)&Al[ar*32 + ah]     = *(const uint4*)ga;
        *(uint4*)&Al[ar*32 + ah + 8] = *(const uint4*)(ga + 8);
        if(tid < BN*4){
            const unsigned short* gb = Wt + (size_t)(nb0+bn)*KdP + k0 + bk;
            *(uint4*)&Bl[bn*32 + bk] = *(const uint4*)gb;
        }
        __syncthreads();
        bf16x8 af[2], bfr[NBF];
        #pragma unroll
        for(int i=0;i<2;i++) af[i] = *(bf16x8*)&Al[(w*32 + i*16 + lm)*32 + lk*8];
        #pragma unroll
        for(int j=0;j<NBF;j++) bfr[j] = *(bf16x8*)&Bl[(j*16 + lm)*32 + lk*8];
        #pragma unroll
        for(int i=0;i<2;i++)
            #pragma unroll
            for(int j=0;j<NBF;j++)
                c[i][j] = __builtin_amdgcn_mfma_f32_16x16x32_bf16(af[i], bfr[j], c[i][j], 0,0,0);
        __syncthreads();
    }
    #pragma unroll
    for(int i=0;i<2;i++){
        int mb = n0 + m0 + w*32 + i*16 + lk*4;
        #pragma unroll
        for(int j=0;j<NBF;j++){
            int col = nb0 + j*16 + lm;
            if(gridDim.z == 1){
                #pragma unroll
                for(int r=0;r<4;r++) acc[(size_t)(mb+r)*Co + col] = c[i][j][r];
            } else {
                #pragma unroll
                for(int r=0;r<4;r++) atomicAdd(&acc[(size_t)(mb+r)*Co + col], c[i][j][r]);
            }
        }
    }
}

// ---------------- conv epilogue ----------------
__global__ void k_finish2(const float* __restrict__ acc, const int* __restrict__ deg,
        const float* __restrict__ xin, const float* __restrict__ root,
        const float* __restrict__ bias, const float* __restrict__ Wa,
        const float* __restrict__ ba, float* __restrict__ y,
        float* __restrict__ att, int N, int Cin, int Co, int NPB){
    extern __shared__ float sm[];
    float* xs  = sm;
    float* red = sm + NPB*Cin;
    int tid = threadIdx.x;
    int nl = tid / Co, co = tid - nl*Co;
    int n = blockIdx.x*NPB + nl;
    bool act = (n < N);
    if(act) for(int c=co; c<Cin; c+=Co) xs[nl*Cin + c] = xin[(size_t)n*Cin + c];
    __syncthreads();
    float yv = 0.f;
    if(act){
        float v = acc[(size_t)n*Co + co] / (float)max(deg[n], 1);
        float rt = 0.f;
        for(int c=0; c<Cin; c++) rt += xs[nl*Cin + c]*root[(size_t)c*Co + co];
        v += rt + bias[co];
        yv = v > 0.f ? v : expm1f(v);
        y[(size_t)n*Co + co] = yv;
    }
    if(att){
        red[tid] = act ? yv * Wa[co*2] : 0.f;
        __syncthreads();
        int cur = Co;
        while(cur > 1){
            int half = (cur+1) >> 1;
            if(co < cur-half) red[nl*Co + co] += red[nl*Co + co + half];
            __syncthreads();
            cur = half;
        }
        if(act && co==0) att[n] = red[nl*Co] + ba[0];
    }
}

// ---------------- pooling (packed argmax) ----------------
__global__ void k_pool_init(unsigned long long* __restrict__ m_p,
        float* __restrict__ cntf, float* __restrict__ ppos, int nc){
    int i = blockIdx.x*blockDim.x + threadIdx.x;
    if(i<nc){
        m_p[i]=0ull; cntf[i]=0.f;
        ppos[i*3]=0.f; ppos[i*3+1]=0.f; ppos[i*3+2]=0.f;
    }
}
__global__ void k_poolA(const float* __restrict__ att, const int* __restrict__ cl,
        unsigned long long* __restrict__ m_p, float* __restrict__ cntf,
        float* __restrict__ ppos, const float* __restrict__ pos, int n){
    int i = blockIdx.x*blockDim.x + threadIdx.x;
    if(i>=n) return;
    int c = cl[i];
    unsigned long long pk = ((unsigned long long)f2ord(att[i]) << 32) | (unsigned)(~i);
    atomicMax(&m_p[c], pk);
    atomicAdd(&cntf[c], 1.f);
    atomicAdd(&ppos[c*3+0], pos[i*3+0]);
    atomicAdd(&ppos[c*3+1], pos[i*3+1]);
    atomicAdd(&ppos[c*3+2], pos[i*3+2]);
}
__global__ void k_pool3(const unsigned long long* __restrict__ m_p, const float* __restrict__ cntf,
        const float* __restrict__ ppos, const float* __restrict__ x,
        float* __restrict__ xo, float* __restrict__ poso, int nc, int Co, int nmax){
    int t = blockIdx.x*blockDim.x + threadIdx.x;
    if(t >= nc*Co) return;
    int c = t / Co;
    int co = t - c*Co;
    unsigned s = ~(unsigned)(m_p[c] & 0xFFFFFFFFull);
    s = min(s, (unsigned)(nmax-1));
    xo[(size_t)c*Co + co] = x[(size_t)s*Co + co];
    if(co < 3) poso[c*3+co] = ppos[c*3+co] / fmaxf(cntf[c], 1.f);
}

// ---------------- final voxel max pool ----------------
__global__ void k_vox(const float* __restrict__ x, const float* __restrict__ pos,
        unsigned* __restrict__ mx_u, float* __restrict__ cnt8){
    int nidx = blockIdx.x, ch = threadIdx.x;
    int v0 = min(max((int)floorf(pos[nidx*3+0]+0.5f),0),1);
    int v1 = min(max((int)floorf(pos[nidx*3+1]+0.5f),0),1);
    int v2 = min(max((int)floorf(pos[nidx*3+2]+0.5f),0),1);
    int b = nidx >> 3;
    int cl = b*8 + v0*4 + v1*2 + v2;
    atomicMax(&mx_u[cl*256+ch], f2ord(x[nidx*256+ch]));
    if(ch==0) atomicAdd(&cnt8[cl], 1.f);
}

// ---------------- FC + log_softmax ----------------
__global__ __launch_bounds__(256) void k_fc(const unsigned* __restrict__ mx_u,
        const float* __restrict__ cnt8, const float* __restrict__ Wfc,
        const float* __restrict__ bfc, float* __restrict__ out){
    __shared__ float sred[10][256];
    int b = blockIdx.x, tid = threadIdx.x;
    float p[10];
    #pragma unroll
    for(int j=0;j<10;j++) p[j]=0.f;
    for(int idx=tid; idx<2048; idx+=256){
        int v = idx >> 8;
        float val = (cnt8[b*8+v] > 0.f) ? ord2f(mx_u[b*2048+idx]) : 0.f;
        const float* wr = &Wfc[idx*10];
        #pragma unroll
        for(int j=0;j<10;j++) p[j] += val*wr[j];
    }
    #pragma unroll
    for(int j=0;j<10;j++) sred[j][tid]=p[j];
    __syncthreads();
    for(int s=128;s>0;s>>=1){
        if(tid<s){
            #pragma unroll
            for(int j=0;j<10;j++) sred[j][tid]+=sred[j][tid+s];
        }
        __syncthreads();
    }
    if(tid==0){
        float lg[10], mx=-1e30f, se=0.f;
        for(int j=0;j<10;j++){ lg[j]=sred[j][0]+bfc[j]; mx=fmaxf(mx,lg[j]); }
        for(int j=0;j<10;j++) se += expf(lg[j]-mx);
        float lse = mx + logf(se);
        for(int j=0;j<10;j++) out[b*10+j] = lg[j]-lse;
    }
}

extern "C" void kernel_launch(void* const* d_in, const int* in_sizes, int n_in,
                              void* d_out, int out_size, void* d_ws, size_t ws_size,
                              hipStream_t stream){
    const float* x0   = (const float*)d_in[0];
    const float* pos0 = (const float*)d_in[1];
    const float *Wc[5], *rootc[5], *bc[5];
    for(int i=0;i<5;i++){
        Wc[i]    = (const float*)d_in[2+3*i];
        rootc[i] = (const float*)d_in[3+3*i];
        bc[i]    = (const float*)d_in[4+3*i];
    }
    const float *Wa[4], *ba[4];
    for(int i=0;i<4;i++){
        Wa[i] = (const float*)d_in[17+2*i];
        ba[i] = (const float*)d_in[18+2*i];
    }
    const float* Wfc = (const float*)d_in[25];
    const float* bfc = (const float*)d_in[26];
    const int* ei[5]; for(int i=0;i<5;i++) ei[i] = (const int*)d_in[27+i];
    const int* cl[4]; for(int i=0;i<4;i++) cl[i] = (const int*)d_in[32+i];

    const int NPG[5]   = {2048,512,128,32,8};
    const int chans[6] = {1,32,64,96,128,256};
    const float inv2r[5] = {5.f,5.f,4.f,2.f,1.f};
    const int B = 32;
    int Ns[5], Es[5], KdPs[5];
    int totN=0, totE=0, totWt=0;
    int nodeBase[5], edgeBase[5], wtBase[5];
    for(int l=0;l<5;l++){
        Ns[l] = B*NPG[l]; Es[l] = Ns[l]*16;
        int Kd = K3*chans[l];
        KdPs[l] = (Kd + 31) & ~31;
        nodeBase[l] = totN; totN += Ns[l];
        edgeBase[l] = totE; totE += Es[l];
        wtBase[l] = totWt; totWt += chans[l+1]*KdPs[l];
    }

    size_t off = 0;
    auto alloc = [&](size_t bytes)->void*{
        void* p = (char*)d_ws + off;
        off = (off + bytes + 255) & ~(size_t)255;
        return p;
    };
    float*    x_a    = (float*)   alloc((size_t)65536*32*4);
    float*    x_b    = (float*)   alloc((size_t)16384*32*4);
    float*    pos_a  = (float*)   alloc((size_t)16384*3*4);
    float*    pos_b  = (float*)   alloc((size_t)4096*3*4);
    float*    acc    = (float*)   alloc((size_t)65536*32*4);
    float*    att    = (float*)   alloc((size_t)65536*4);
    unsigned long long* m_p = (unsigned long long*)alloc((size_t)16384*8);
    float*    cntf   = (float*)   alloc((size_t)16384*4);
    float*    ppos   = (float*)   alloc((size_t)16384*3*4);
    unsigned* mx_u   = (unsigned*)alloc((size_t)256*256*4);
    float*    cnt8   = (float*)   alloc((size_t)256*4);
    int*      deg_a  = (int*)     alloc((size_t)totN*4);
    int*      rowp_a = (int*)     alloc((size_t)(totN+5)*4);
    int*      curs_a = (int*)     alloc((size_t)totN*4);
    int*      elist_a= (int*)     alloc((size_t)totE*4);
    int*      bsum   = (int*)     alloc((size_t)32*4);
    unsigned short* Wt_a = (unsigned short*)alloc((size_t)totWt*2);
    unsigned short* A  = (unsigned short*)((char*)d_ws + off);
    size_t Abudget   = (ws_size > off) ? (ws_size - off) : 0;

    CsrArgs ca; WtArgs wa;
    for(int l=0;l<5;l++){
        ca.dst[l] = ei[l] + Es[l];
        ca.deg[l] = deg_a + nodeBase[l];
        ca.elist[l] = elist_a + edgeBase[l];
        ca.E[l] = Es[l]; ca.N[l] = Ns[l];
        wa.W[l] = Wc[l]; wa.Wt[l] = Wt_a + wtBase[l];
        wa.Kd[l] = K3*chans[l]; wa.KdP[l] = KdPs[l]; wa.Co[l] = chans[l+1];
    }

    // scan block table: 4096 nodes per block
    ScanTbl st;
    int nblk = 0;
    for(int l=0;l<5;l++){
        st.lfirst[l] = nblk;
        for(int ls=0; ls<Ns[l]; ls+=4096){
            st.degOff[nblk] = nodeBase[l] + ls;
            st.rpOff[nblk]  = nodeBase[l] + l + ls;
            st.curOff[nblk] = nodeBase[l] + ls;
            st.cnt[nblk]    = (Ns[l]-ls < 4096) ? (Ns[l]-ls) : 4096;
            nblk++;
        }
        st.rpNOff[l] = nodeBase[l] + l + Ns[l];
        st.Eval[l]   = Es[l];
    }
    st.lfirst[5] = nblk;

    hipMemsetAsync(deg_a, 0, (size_t)totN*4, stream);
    k_deg_all<<<dim3(4096,5), 256, 0, stream>>>(ca);
    k_scanA<<<nblk, 256, 0, stream>>>(st, deg_a, rowp_a, bsum);
    k_scanB<<<1, 64, 0, stream>>>(st, bsum, rowp_a);
    k_scanC<<<nblk, 256, 0, stream>>>(st, rowp_a, bsum, curs_a);
    k_fill_all2<<<dim3(4096,5), 256, 0, stream>>>(ca, curs_a+nodeBase[0], curs_a+nodeBase[1],
        curs_a+nodeBase[2], curs_a+nodeBase[3], curs_a+nodeBase[4]);
    k_wt_all<<<dim3(250,4,5), 256, 0, stream>>>(wa);

    const float* xin = x0;
    const float* pin = pos0;

    for(int L=0; L<5; L++){
        int N  = Ns[L];
        int Cin = chans[L], Co = chans[L+1];
        int KdP = KdPs[L];
        const int* srcp = ei[L];
        const int* rowptrL = rowp_a + nodeBase[L] + L;
        const int* elistL  = ca.elist[L];
        const unsigned short* WtL = wa.Wt[L];
        const int* degL = ca.deg[L];

        hipMemsetAsync(acc, 0, (size_t)N*Co*4, stream);

        size_t nodeb = (size_t)KdP*2;
        int Mc = (int)(Abudget / nodeb);
        Mc = (Mc / 128) * 128;
        if(Mc < 128) Mc = 128;
        if(Mc > N) Mc = N;

        for(int rn0=0; rn0<N; rn0+=Mc){
            int rn1 = (rn0+Mc < N) ? rn0+Mc : N;
            int Mr  = rn1 - rn0;
            if(Cin==1)        k_build1      <<<Mr/32, 256, 0, stream>>>(srcp, pin, xin, rowptrL, elistL, inv2r[L], rn0, KdP, A);
            else if(Cin==32)  k_build2<32>  <<<Mr,    256, 0, stream>>>(srcp, pin, xin, rowptrL, elistL, inv2r[L], rn0, KdP, A);
            else if(Cin==64)  k_build2<64>  <<<Mr,    256, 0, stream>>>(srcp, pin, xin, rowptrL, elistL, inv2r[L], rn0, KdP, A);
            else if(Cin==96)  k_build2<96>  <<<Mr,    256, 0, stream>>>(srcp, pin, xin, rowptrL, elistL, inv2r[L], rn0, KdP, A);
            else              k_build2<128> <<<Mr,    256, 0, stream>>>(srcp, pin, xin, rowptrL, elistL, inv2r[L], rn0, KdP, A);

            int BN = (Co % 64 == 0) ? 64 : 32;
            int gx = Mr/128, gy = Co/BN;
            int S = 768/(gx*gy);
            if(S < 1) S = 1;
            int maxS = KdP/32;
            if(S > maxS) S = maxS;
            int Kper = ((KdP + S - 1)/S + 31) & ~31;
            S = (KdP + Kper - 1)/Kper;
            dim3 g(gx, gy, S);
            if(BN == 64) k_mfma<64><<<g, 256, 0, stream>>>(A, WtL, acc, rn0, Co, KdP, Kper);
            else         k_mfma<32><<<g, 256, 0, stream>>>(A, WtL, acc, rn0, Co, KdP, Kper);
        }

        float* y = x_a;
        int NPB = 256/Co; if(NPB < 1) NPB = 1;
        int thr = NPB*Co;
        size_t smb = (size_t)(NPB*Cin + NPB*Co)*4;
        k_finish2<<<(N+NPB-1)/NPB, thr, smb, stream>>>(acc, degL, xin, rootc[L], bc[L],
            (L<4)?Wa[L]:nullptr, (L<4)?ba[L]:nullptr, y, (L<4)?att:nullptr, N, Cin, Co, NPB);

        if(L<4){
            int nc = Ns[L+1];
            float* pout = (L%2==0) ? pos_a : pos_b;
            k_pool_init<<<(nc+255)/256, 256, 0, stream>>>(m_p, cntf, ppos, nc);
            k_poolA<<<(N+255)/256, 256, 0, stream>>>(att, cl[L], m_p, cntf, ppos, pin, N);
            k_pool3<<<(nc*Co+255)/256, 256, 0, stream>>>(m_p, cntf, ppos, y, x_b, pout, nc, Co, N);
            xin = x_b; pin = pout;
        }
    }

    hipMemsetAsync(mx_u, 0, (size_t)(256*256*4 + 256*4), stream);
    k_vox<<<256, 256, 0, stream>>>(x_a, pin, mx_u, cnt8);
    k_fc<<<32, 256, 0, stream>>>(mx_u, cnt8, Wfc, bfc, (float*)d_out);
}